// Round 6
// baseline (419.504 us; speedup 1.0000x reference)
//
#include <hip/hip_runtime.h>
#include <hip/hip_bf16.h>
#include <math.h>

// EntityAwareAttention on MI355X.
// K1: W_hid -> bf16, transposed/padded [22 kchunks][64 a][32 k]
// K2: u2[b][a] entity projection (fp32), 2 batches per block, grid 1024
// K3: PERSISTENT main kernel, grid 768 (3 blocks/CU), each block grid-strides
//     over (b, 16-token) tiles with DOUBLE-BUFFERED LDS X halves:
//       - W fragments + v loaded ONCE per block (22x short8 = 88 VGPR)
//       - per iteration: MFMA(half h) -> issue next tile's HBM loads under
//         the epilogue/softmax/z phases -> convert+write into half h^1
//       - 3 barriers per iteration, staging latency hidden in-block.
// K4: combine 8 partials per b (log-sum-exp merge), write z.

#define B_    2048
#define L_    128
#define H2_   600
#define P_    50
#define A_    50
#define D700  700
#define KCN   22      // ceil(700/32) -> 704
#define AP    64      // padded attention dim
#define MT    16      // tokens per tile
#define XP    712     // Xs row stride in bf16 elems (704 data + 8 pad)
#define GRIDM 768
#define NBQ   (B_ * 8)

typedef __attribute__((ext_vector_type(8))) short short8;
typedef __attribute__((ext_vector_type(4))) float f32x4;

__device__ __forceinline__ unsigned short f2bf(float f) {
  unsigned u = __float_as_uint(f);
  u += 0x7fffu + ((u >> 16) & 1u);   // round-to-nearest-even
  return (unsigned short)(u >> 16);
}
__device__ __forceinline__ unsigned pk2(float lo, float hi) {
  return (unsigned)f2bf(lo) | ((unsigned)f2bf(hi) << 16);
}
__device__ __forceinline__ float bf2f(unsigned short s) {
  return __uint_as_float(((unsigned)s) << 16);
}

// ---------------- K1: prep W_hid -> bf16 chunked [kc][a][k] ----------------
__global__ __launch_bounds__(256) void kwprep(const float* __restrict__ Wh,
                                              unsigned short* __restrict__ Wt) {
  int idx = blockIdx.x * 256 + threadIdx.x;
  if (idx >= KCN * 2048) return;
  int kc = idx >> 11, r = idx & 2047, a = r >> 5, kk = r & 31;
  int d = kc * 32 + kk;
  float v = (a < A_ && d < D700) ? Wh[a * D700 + d] : 0.f;
  Wt[idx] = f2bf(v);
}

// ---------------- K2: u2[b][0..63] (fp32), 2 b's per block ----------------
__global__ __launch_bounds__(256) void ku2(const float* __restrict__ hidden,
                                           const int* __restrict__ e1,
                                           const int* __restrict__ e2,
                                           const float* __restrict__ Went,
                                           const float* __restrict__ lt,
                                           float* __restrict__ u2ws) {
  __shared__ __align__(16) float E[2][2400];   // [hid_e1|e1_type|hid_e2|e2_type]
  __shared__ float dots[2][2][3];
  __shared__ float aw[2][2][3];
  int tid = threadIdx.x;
  int b0 = blockIdx.x * 2;

  for (int idx = tid; idx < 2 * 2 * 150; idx += 256) {
    int i = idx / 300, r = idx - i * 300, e = r / 150, g = r - e * 150;
    int bb = b0 + i;
    int l = e ? e2[bb] : e1[bb];
    float4 f = *(const float4*)(hidden + ((size_t)bb * L_ + l) * H2_ + g * 4);
    *(float4*)(&E[i][e * 1200 + g * 4]) = f;
  }
  __syncthreads();

  int w = tid >> 6, lane = tid & 63;
  for (int task = w * 3; task < w * 3 + 3; ++task) {
    int i = task / 6, e = (task / 3) & 1, t = task % 3;
    float p = 0.f;
    for (int d = lane; d < 600; d += 64) p += E[i][e * 1200 + d] * lt[t * 600 + d];
    #pragma unroll
    for (int mask = 1; mask <= 32; mask <<= 1) p += __shfl_xor(p, mask);
    if (lane == 0) dots[i][e][t] = p;
  }
  __syncthreads();
  if (tid < 12) {
    int t = tid % 3, e = (tid / 3) & 1, i = tid / 6;
    float d0 = dots[i][e][0], d1 = dots[i][e][1], d2 = dots[i][e][2];
    float m = fmaxf(d0, fmaxf(d1, d2));
    float x0 = expf(d0 - m), x1 = expf(d1 - m), x2 = expf(d2 - m);
    float Z = x0 + x1 + x2;
    aw[i][e][t] = ((t == 0) ? x0 : (t == 1) ? x1 : x2) / Z;
  }
  __syncthreads();
  for (int idx = tid; idx < 2 * 2 * 600; idx += 256) {
    int i = idx / 1200, r = idx - i * 1200, e = r / 600, d = r - e * 600;
    float v = aw[i][e][0] * lt[d] + aw[i][e][1] * lt[600 + d] + aw[i][e][2] * lt[1200 + d];
    E[i][e * 1200 + 600 + d] = v;
  }
  __syncthreads();
  for (int a = w; a < A_; a += 4) {
    float acc[2] = {0.f, 0.f};
    for (int d0 = lane * 4; d0 < 2400; d0 += 256) {
      float4 wv = *(const float4*)(Went + a * 2400 + d0);
      #pragma unroll
      for (int i = 0; i < 2; ++i) {
        float4 ev = *(const float4*)(&E[i][d0]);
        acc[i] += ev.x * wv.x + ev.y * wv.y + ev.z * wv.z + ev.w * wv.w;
      }
    }
    #pragma unroll
    for (int i = 0; i < 2; ++i) {
      float p = acc[i];
      #pragma unroll
      for (int mask = 1; mask <= 32; mask <<= 1) p += __shfl_xor(p, mask);
      if (lane == 0) u2ws[(b0 + i) * AP + a] = p;
    }
  }
  for (int idx = tid; idx < 2 * (AP - A_); idx += 256) {
    u2ws[(b0 + idx / (AP - A_)) * AP + A_ + idx % (AP - A_)] = 0.f;
  }
}

// ---------------- K3: persistent main fused kernel ----------------
__global__ __launch_bounds__(256, 3) void kmain(
    const float* __restrict__ hidden, const float* __restrict__ pos1,
    const float* __restrict__ pos2, const float* __restrict__ vvec,
    const unsigned short* __restrict__ Wt, const float* __restrict__ u2ws,
    float* __restrict__ zp_ws, float* __restrict__ mS_ws) {
  __shared__ __align__(16) unsigned short Xs[2][MT * XP];   // 2 x 22,784 B
  __shared__ float scores4[4][MT];
  __shared__ float es_s[MT];

  int tid = threadIdx.x;
  int lane = tid & 63, wvix = tid >> 6;
  int acol = lane & 15, kgrp = lane >> 4;
  int t = tid >> 4, c0 = tid & 15;
  bool h10 = (c0 < 6);
  bool hq = (tid < 144);
  int aidx = wvix * 16 + acol;

  // ---- per-block persistent state: W fragments + v
  const unsigned short* wbase = Wt + aidx * 32 + kgrp * 8;
  short8 wf[KCN];
  #pragma unroll
  for (int kc = 0; kc < KCN; ++kc) wf[kc] = *(const short8*)(wbase + kc * 2048);
  float va = (aidx < A_) ? vvec[aidx] : 0.f;

  // zero-pad cols 700..703 in both halves (never overwritten by staging)
  if (tid < 64) {
    int hh = tid >> 5, r = tid & 31, rr = r >> 1, g = r & 1;
    *(unsigned*)(&Xs[hh][rr * XP + 700 + g * 2]) = 0u;
  }

  // ---- prologue: deep-stage first tile into half 0
  int bq = blockIdx.x;
  float u2cur;
  {
    int b = bq >> 3, tok0 = (bq & 7) * MT;
    const float* rowp = hidden + ((size_t)(b * L_ + tok0) + t) * H2_;
    float4 f[9]; float4 f9 = {0.f, 0.f, 0.f, 0.f};
    #pragma unroll
    for (int j = 0; j < 9; ++j) f[j] = *(const float4*)(rowp + (c0 + 16 * j) * 4);
    if (h10) f9 = *(const float4*)(rowp + (c0 + 144) * 4);
    const float* p1 = pos1 + (size_t)(b * L_ + tok0) * P_;
    const float* p2 = pos2 + (size_t)(b * L_ + tok0) * P_;
    float2 q1a = *(const float2*)(p1 + tid * 2);
    float2 q2a = *(const float2*)(p2 + tid * 2);
    float2 q1b = {0.f, 0.f}, q2b = {0.f, 0.f};
    if (hq) {
      q1b = *(const float2*)(p1 + (tid + 256) * 2);
      q2b = *(const float2*)(p2 + (tid + 256) * 2);
    }
    u2cur = u2ws[b * AP + aidx];
    #pragma unroll
    for (int j = 0; j < 9; ++j) {
      uint2 w; w.x = pk2(f[j].x, f[j].y); w.y = pk2(f[j].z, f[j].w);
      *(uint2*)(&Xs[0][t * XP + (c0 + 16 * j) * 4]) = w;
    }
    if (h10) {
      uint2 w; w.x = pk2(f9.x, f9.y); w.y = pk2(f9.z, f9.w);
      *(uint2*)(&Xs[0][t * XP + (c0 + 144) * 4]) = w;
    }
    {
      int t1 = tid / 25, g = tid - t1 * 25;
      *(unsigned*)(&Xs[0][t1 * XP + 600 + g * 2]) = pk2(q1a.x, q1a.y);
      *(unsigned*)(&Xs[0][t1 * XP + 650 + g * 2]) = pk2(q2a.x, q2a.y);
    }
    if (hq) {
      int idx = tid + 256;
      int t1 = idx / 25, g = idx - t1 * 25;
      *(unsigned*)(&Xs[0][t1 * XP + 600 + g * 2]) = pk2(q1b.x, q1b.y);
      *(unsigned*)(&Xs[0][t1 * XP + 650 + g * 2]) = pk2(q2b.x, q2b.y);
    }
  }
  __syncthreads();

  // ---- persistent loop
  int h = 0;
  while (true) {
    int bqn = bq + GRIDM;
    bool hasnext = (bqn < NBQ);
    int bn = bqn >> 3, tok0n = (bqn & 7) * MT;
    const float* rowpn = hidden + ((size_t)(bn * L_ + tok0n) + t) * H2_;

    // -- MFMA over half h (barrier-free)
    f32x4 acc = {0.f, 0.f, 0.f, 0.f};
    #pragma unroll
    for (int kc = 0; kc < KCN; ++kc) {
      short8 a0 = *(const short8*)(&Xs[h][acol * XP + kc * 32 + kgrp * 8]);
      acc = __builtin_amdgcn_mfma_f32_16x16x32_bf16(a0, wf[kc], acc, 0, 0, 0);
    }

    // -- issue batch A of next tile's loads (latency hides under epilogue)
    float4 fA[5];
    if (hasnext) {
      #pragma unroll
      for (int j = 0; j < 5; ++j) fA[j] = *(const float4*)(rowpn + (c0 + 16 * j) * 4);
    }

    // -- epilogue: scores = sum_a v[a]*tanh(u1+u2)
    {
      float s0[4];
      #pragma unroll
      for (int r = 0; r < 4; ++r) s0[r] = va * tanhf(acc[r] + u2cur);
      #pragma unroll
      for (int mask = 1; mask < 16; mask <<= 1) {
        #pragma unroll
        for (int r = 0; r < 4; ++r) s0[r] += __shfl_xor(s0[r], mask);
      }
      if (acol == 0) {
        #pragma unroll
        for (int r = 0; r < 4; ++r) scores4[wvix][kgrp * 4 + r] = s0[r];
      }
    }
    __syncthreads();   // B1

    // -- partial softmax over 16 tokens (wave 0)
    if (tid < 64) {
      float s = (tid < MT)
                    ? (scores4[0][tid] + scores4[1][tid] + scores4[2][tid] + scores4[3][tid])
                    : -3.402823466e38f;
      float m = s;
      #pragma unroll
      for (int mask = 1; mask <= 32; mask <<= 1) m = fmaxf(m, __shfl_xor(m, mask));
      float e = (tid < MT) ? expf(s - m) : 0.f;
      float S = e;
      #pragma unroll
      for (int mask = 1; mask <= 32; mask <<= 1) S += __shfl_xor(S, mask);
      if (tid < MT) es_s[tid] = e;
      if (tid == 0) { mS_ws[bq * 2] = m; mS_ws[bq * 2 + 1] = S; }
    }

    // -- issue batch B + convert/write batch A into half h^1
    float4 fB[5] = {};
    float2 q1a = {0.f, 0.f}, q2a = {0.f, 0.f}, q1b = {0.f, 0.f}, q2b = {0.f, 0.f};
    float u2n = 0.f;
    if (hasnext) {
      #pragma unroll
      for (int j = 0; j < 4; ++j) fB[j] = *(const float4*)(rowpn + (c0 + 16 * (5 + j)) * 4);
      if (h10) fB[4] = *(const float4*)(rowpn + (c0 + 144) * 4);
      const float* p1n = pos1 + (size_t)(bn * L_ + tok0n) * P_;
      const float* p2n = pos2 + (size_t)(bn * L_ + tok0n) * P_;
      q1a = *(const float2*)(p1n + tid * 2);
      q2a = *(const float2*)(p2n + tid * 2);
      if (hq) {
        q1b = *(const float2*)(p1n + (tid + 256) * 2);
        q2b = *(const float2*)(p2n + (tid + 256) * 2);
      }
      u2n = u2ws[bn * AP + aidx];
      unsigned short* Xn = &Xs[h ^ 1][0];
      #pragma unroll
      for (int j = 0; j < 5; ++j) {
        uint2 w; w.x = pk2(fA[j].x, fA[j].y); w.y = pk2(fA[j].z, fA[j].w);
        *(uint2*)(&Xn[t * XP + (c0 + 16 * j) * 4]) = w;
      }
    }
    __syncthreads();   // B2

    // -- z-partial from half h
    if (tid < 75) {
      float zacc[8] = {0.f, 0.f, 0.f, 0.f, 0.f, 0.f, 0.f, 0.f};
      #pragma unroll
      for (int tt = 0; tt < MT; ++tt) {
        short8 xv = *(const short8*)(&Xs[h][tt * XP + tid * 8]);
        float e = es_s[tt];
        #pragma unroll
        for (int j = 0; j < 8; ++j) zacc[j] += e * bf2f((unsigned short)xv[j]);
      }
      float4 w0 = {zacc[0], zacc[1], zacc[2], zacc[3]};
      float4 w1 = {zacc[4], zacc[5], zacc[6], zacc[7]};
      *(float4*)(zp_ws + (size_t)bq * 600 + tid * 8) = w0;
      *(float4*)(zp_ws + (size_t)bq * 600 + tid * 8 + 4) = w1;
    }

    // -- convert/write batch B into half h^1
    if (hasnext) {
      unsigned short* Xn = &Xs[h ^ 1][0];
      #pragma unroll
      for (int j = 0; j < 4; ++j) {
        uint2 w; w.x = pk2(fB[j].x, fB[j].y); w.y = pk2(fB[j].z, fB[j].w);
        *(uint2*)(&Xn[t * XP + (c0 + 16 * (5 + j)) * 4]) = w;
      }
      if (h10) {
        uint2 w; w.x = pk2(fB[4].x, fB[4].y); w.y = pk2(fB[4].z, fB[4].w);
        *(uint2*)(&Xn[t * XP + (c0 + 144) * 4]) = w;
      }
      {
        int t1 = tid / 25, g = tid - t1 * 25;
        *(unsigned*)(&Xn[t1 * XP + 600 + g * 2]) = pk2(q1a.x, q1a.y);
        *(unsigned*)(&Xn[t1 * XP + 650 + g * 2]) = pk2(q2a.x, q2a.y);
      }
      if (hq) {
        int idx = tid + 256;
        int t1 = idx / 25, g = idx - t1 * 25;
        *(unsigned*)(&Xn[t1 * XP + 600 + g * 2]) = pk2(q1b.x, q1b.y);
        *(unsigned*)(&Xn[t1 * XP + 650 + g * 2]) = pk2(q2b.x, q2b.y);
      }
      u2cur = u2n;
    }
    __syncthreads();   // B4
    if (!hasnext) break;
    h ^= 1;
    bq = bqn;
  }
}

// ---------------- K4: combine 8 partials per b ----------------
__global__ __launch_bounds__(128) void kcomb(const float* __restrict__ zp_ws,
                                             const float* __restrict__ mS_ws,
                                             float* __restrict__ out) {
  int b = blockIdx.x, tid = threadIdx.x;
  float mq[8], Sq[8];
  #pragma unroll
  for (int qq = 0; qq < 8; ++qq) {
    mq[qq] = mS_ws[(b * 8 + qq) * 2];
    Sq[qq] = mS_ws[(b * 8 + qq) * 2 + 1];
  }
  float M = mq[0];
  #pragma unroll
  for (int qq = 1; qq < 8; ++qq) M = fmaxf(M, mq[qq]);
  float c[8], Z = 0.f;
  #pragma unroll
  for (int qq = 0; qq < 8; ++qq) { c[qq] = expf(mq[qq] - M); Z += Sq[qq] * c[qq]; }
  float inv = 1.f / Z;
  for (int d = tid; d < 600; d += 128) {
    float z = 0.f;
    #pragma unroll
    for (int qq = 0; qq < 8; ++qq) z += c[qq] * zp_ws[(size_t)(b * 8 + qq) * 600 + d];
    out[b * 600 + d] = z * inv;
  }
}

extern "C" void kernel_launch(void* const* d_in, const int* in_sizes, int n_in,
                              void* d_out, int out_size, void* d_ws, size_t ws_size,
                              hipStream_t stream) {
  const float* hidden = (const float*)d_in[0];
  const float* pos1   = (const float*)d_in[1];
  const float* pos2   = (const float*)d_in[2];
  const int*   e1     = (const int*)d_in[3];
  const int*   e2     = (const int*)d_in[4];
  const float* Whid   = (const float*)d_in[5];
  const float* Went   = (const float*)d_in[6];
  const float* lt     = (const float*)d_in[7];
  const float* vvec   = (const float*)d_in[8];
  float* out = (float*)d_out;

  char* ws = (char*)d_ws;
  unsigned short* Wt = (unsigned short*)ws;                       //  90,112 B (pad 98,304)
  float* u2ws  = (float*)(ws + 98304);                            // 524,288 B
  float* mS_ws = (float*)(ws + 98304 + 524288);                   // 131,072 B
  float* zp_ws = (float*)(ws + 98304 + 524288 + 131072);          // 39,321,600 B

  hipLaunchKernelGGL(kwprep, dim3(176), dim3(256), 0, stream, Whid, Wt);
  hipLaunchKernelGGL(ku2, dim3(B_ / 2), dim3(256), 0, stream, hidden, e1, e2, Went, lt, u2ws);
  hipLaunchKernelGGL(kmain, dim3(GRIDM), dim3(256), 0, stream, hidden, pos1, pos2, vvec,
                     Wt, u2ws, zp_ws, mS_ws);
  hipLaunchKernelGGL(kcomb, dim3(B_), dim3(128), 0, stream, zp_ws, mS_ws, out);
}

// Round 9
// 265.434 us; speedup vs baseline: 1.5804x; 1.5804x over previous
//
#include <hip/hip_runtime.h>
#include <hip/hip_bf16.h>
#include <math.h>

// EntityAwareAttention on MI355X.
// K1: W_hid -> bf16, transposed/padded [22 kchunks][64 a][32 k]
// K2: u2[b][a] entity projection (fp32), 2 batches per block
// K3: main fused kernel, one block per (b, 16-token tile):
//       hidden staged as FP32 via global_load_lds (16B calls, 40/block,
//       XOR-swizzled SOURCE + linear LDS dest; read side applies the same
//       involution => bank-conflict-free ds_read_b128),
//       pos1/pos2 staged fp32 into a small identically-swizzled region,
//       A-fragments built at read time via v_cvt_pk_bf16_f32,
//       W fragments in registers (22 x short8), barrier-free MFMA K-loop,
//       scores=v.tanh(u1+u2), partial softmax, z-partial from fp32 LDS.
// K4: combine 8 partials per b (log-sum-exp merge), write z.

#define B_    2048
#define L_    128
#define H2_   600
#define P_    50
#define A_    50
#define D700  700
#define KCN   22      // ceil(700/32) -> 704
#define AP    64      // padded attention dim
#define MT    16      // tokens per tile
#define RS    2560    // Xh row stride bytes (640 fp32)
#define XPOFF 40960   // pos region byte offset in LDSX
#define PRS   512     // pos row stride bytes (128 fp32)

typedef __attribute__((ext_vector_type(8))) short short8;
typedef __attribute__((ext_vector_type(4))) float f32x4;

union U8 { unsigned u[4]; short8 s; };

__device__ __forceinline__ unsigned short f2bf(float f) {
  unsigned u = __float_as_uint(f);
  u += 0x7fffu + ((u >> 16) & 1u);   // round-to-nearest-even
  return (unsigned short)(u >> 16);
}
__device__ __forceinline__ unsigned pk2(float lo, float hi) {
  return (unsigned)f2bf(lo) | ((unsigned)f2bf(hi) << 16);
}
__device__ __forceinline__ unsigned cvtpk(float a, float b) {
  unsigned r;
  asm("v_cvt_pk_bf16_f32 %0, %1, %2" : "=v"(r) : "v"(a), "v"(b));
  return r;
}
__device__ __forceinline__ short8 mkfrag(float4 lo, float4 hi) {
  U8 t;
  t.u[0] = cvtpk(lo.x, lo.y);
  t.u[1] = cvtpk(lo.z, lo.w);
  t.u[2] = cvtpk(hi.x, hi.y);
  t.u[3] = cvtpk(hi.z, hi.w);
  return t.s;
}
__device__ __forceinline__ void gload16(const void* g, void* l) {
  __builtin_amdgcn_global_load_lds(
      (const __attribute__((address_space(1))) unsigned int*)g,
      (__attribute__((address_space(3))) unsigned int*)l, 16, 0, 0);
}

// ---------------- K1: prep W_hid -> bf16 chunked [kc][a][k] ----------------
__global__ __launch_bounds__(256) void kwprep(const float* __restrict__ Wh,
                                              unsigned short* __restrict__ Wt) {
  int idx = blockIdx.x * 256 + threadIdx.x;
  if (idx >= KCN * 2048) return;
  int kc = idx >> 11, r = idx & 2047, a = r >> 5, kk = r & 31;
  int d = kc * 32 + kk;
  float v = (a < A_ && d < D700) ? Wh[a * D700 + d] : 0.f;
  Wt[idx] = f2bf(v);
}

// ---------------- K2: u2[b][0..63] (fp32), 2 b's per block ----------------
__global__ __launch_bounds__(256) void ku2(const float* __restrict__ hidden,
                                           const int* __restrict__ e1,
                                           const int* __restrict__ e2,
                                           const float* __restrict__ Went,
                                           const float* __restrict__ lt,
                                           float* __restrict__ u2ws) {
  __shared__ __align__(16) float E[2][2400];
  __shared__ float dots[2][2][3];
  __shared__ float aw[2][2][3];
  int tid = threadIdx.x;
  int b0 = blockIdx.x * 2;

  for (int idx = tid; idx < 2 * 2 * 150; idx += 256) {
    int i = idx / 300, r = idx - i * 300, e = r / 150, g = r - e * 150;
    int bb = b0 + i;
    int l = e ? e2[bb] : e1[bb];
    float4 f = *(const float4*)(hidden + ((size_t)bb * L_ + l) * H2_ + g * 4);
    *(float4*)(&E[i][e * 1200 + g * 4]) = f;
  }
  __syncthreads();

  int w = tid >> 6, lane = tid & 63;
  for (int task = w * 3; task < w * 3 + 3; ++task) {
    int i = task / 6, e = (task / 3) & 1, t = task % 3;
    float p = 0.f;
    for (int d = lane; d < 600; d += 64) p += E[i][e * 1200 + d] * lt[t * 600 + d];
    #pragma unroll
    for (int mask = 1; mask <= 32; mask <<= 1) p += __shfl_xor(p, mask);
    if (lane == 0) dots[i][e][t] = p;
  }
  __syncthreads();
  if (tid < 12) {
    int t = tid % 3, e = (tid / 3) & 1, i = tid / 6;
    float d0 = dots[i][e][0], d1 = dots[i][e][1], d2 = dots[i][e][2];
    float m = fmaxf(d0, fmaxf(d1, d2));
    float x0 = expf(d0 - m), x1 = expf(d1 - m), x2 = expf(d2 - m);
    float Z = x0 + x1 + x2;
    aw[i][e][t] = ((t == 0) ? x0 : (t == 1) ? x1 : x2) / Z;
  }
  __syncthreads();
  for (int idx = tid; idx < 2 * 2 * 600; idx += 256) {
    int i = idx / 1200, r = idx - i * 1200, e = r / 600, d = r - e * 600;
    float v = aw[i][e][0] * lt[d] + aw[i][e][1] * lt[600 + d] + aw[i][e][2] * lt[1200 + d];
    E[i][e * 1200 + 600 + d] = v;
  }
  __syncthreads();
  for (int a = w; a < A_; a += 4) {
    float acc[2] = {0.f, 0.f};
    for (int d0 = lane * 4; d0 < 2400; d0 += 256) {
      float4 wv = *(const float4*)(Went + a * 2400 + d0);
      #pragma unroll
      for (int i = 0; i < 2; ++i) {
        float4 ev = *(const float4*)(&E[i][d0]);
        acc[i] += ev.x * wv.x + ev.y * wv.y + ev.z * wv.z + ev.w * wv.w;
      }
    }
    #pragma unroll
    for (int i = 0; i < 2; ++i) {
      float p = acc[i];
      #pragma unroll
      for (int mask = 1; mask <= 32; mask <<= 1) p += __shfl_xor(p, mask);
      if (lane == 0) u2ws[(b0 + i) * AP + a] = p;
    }
  }
  for (int idx = tid; idx < 2 * (AP - A_); idx += 256) {
    u2ws[(b0 + idx / (AP - A_)) * AP + A_ + idx % (AP - A_)] = 0.f;
  }
}

// ---------------- K3: main fused kernel ----------------
__global__ __launch_bounds__(256, 3) void kmain(
    const float* __restrict__ hidden, const float* __restrict__ pos1,
    const float* __restrict__ pos2, const float* __restrict__ vvec,
    const unsigned short* __restrict__ Wt, const float* __restrict__ u2ws,
    float* __restrict__ zp_ws, float* __restrict__ mS_ws) {
  __shared__ __align__(16) char LDSX[XPOFF + MT * PRS];   // 49,152 B
  __shared__ float scores4[4][MT];
  __shared__ float es_s[MT];

  int tid = threadIdx.x;
  int bq = blockIdx.x;
  int b = bq >> 3, o = bq & 7, tok0 = o * MT;
  int lane = tid & 63, wvix = tid >> 6;
  int acol = lane & 15, kgrp = lane >> 4;
  int aidx = wvix * 16 + acol;

  // ---- W fragments -> registers (L2-resident), issued first
  const unsigned short* wbase = Wt + aidx * 32 + kgrp * 8;
  short8 wf[KCN];
  #pragma unroll
  for (int kc = 0; kc < KCN; ++kc) wf[kc] = *(const short8*)(wbase + kc * 2048);

  float u2cur = u2ws[b * AP + aidx];
  float va = (aidx < A_) ? vvec[aidx] : 0.f;

  // ---- hidden -> LDS fp32 via global_load_lds, pre-swizzled source
  // slot D holds hidden row r byte ((D%RS) ^ ((r&7)<<4)); garbage (clamped)
  // only lands in slots whose content-col >= 600 (never consumed).
  const char* hb = (const char*)(hidden + (size_t)(b * L_ + tok0) * H2_);
  #pragma unroll
  for (int j = 0; j < 10; ++j) {
    int D = (wvix * 10 + j) * 1024 + lane * 16;
    int r = D / RS;
    int off = D - r * RS;
    int so = off ^ ((r & 7) << 4);
    if (so >= 2400) so = 0;   // pad-content slot: clamp (stays in-bounds)
    gload16(hb + r * 2400 + so, LDSX + (wvix * 10 + j) * 1024);
  }

  // ---- pos1/pos2 -> swizzled fp32 region (reg-staged, small)
  const float* p1 = pos1 + (size_t)(b * L_ + tok0) * P_;
  const float* p2 = pos2 + (size_t)(b * L_ + tok0) * P_;
  {
    int fl = tid * 2, r = fl / 50, c = fl - 50 * r;
    int xr = (r & 7) << 4;
    float2 a1 = *(const float2*)(p1 + fl);
    float2 a2 = *(const float2*)(p2 + fl);
    char* Lp = LDSX + XPOFF + r * PRS;
    *(float*)(Lp + ((c * 4) ^ xr)) = a1.x;
    *(float*)(Lp + (((c + 1) * 4) ^ xr)) = a1.y;
    *(float*)(Lp + ((200 + c * 4) ^ xr)) = a2.x;
    *(float*)(Lp + ((200 + (c + 1) * 4) ^ xr)) = a2.y;
  }
  if (tid < 144) {
    int fl = (tid + 256) * 2, r = fl / 50, c = fl - 50 * r;
    int xr = (r & 7) << 4;
    float2 a1 = *(const float2*)(p1 + fl);
    float2 a2 = *(const float2*)(p2 + fl);
    char* Lp = LDSX + XPOFF + r * PRS;
    *(float*)(Lp + ((c * 4) ^ xr)) = a1.x;
    *(float*)(Lp + (((c + 1) * 4) ^ xr)) = a1.y;
    *(float*)(Lp + ((200 + c * 4) ^ xr)) = a2.x;
    *(float*)(Lp + ((200 + (c + 1) * 4) ^ xr)) = a2.y;
  }
  if (tid < 64) {   // zero content floats 100..103 (k=700..703)
    int r = tid >> 2, c = 100 + (tid & 3);
    int xr = (r & 7) << 4;
    *(float*)(LDSX + XPOFF + r * PRS + ((c * 4) ^ xr)) = 0.f;
  }
  __syncthreads();

  // ---- per-lane constant LDS bases: lo(kc) = base + kc*128, hi = lo^16
  int rr = acol;
  int xr = (rr & 7) << 4;
  int kgp = kgrp ^ ((rr >> 1) & 3);
  int bh = rr * RS + (kgp << 5) + ((rr & 1) << 4);
  int Cg = ((kgrp + 1) & 3) << 5;
  int bp = XPOFF + rr * PRS + (kgrp * 32 - 2400 - Cg) + (Cg ^ (xr & 0x60)) + (xr & 0x10);

  // ---- MFMA K-loop: D[16 tok][64 a]; two acc chains
  f32x4 accA = {0.f, 0.f, 0.f, 0.f}, accB = {0.f, 0.f, 0.f, 0.f};
  #pragma unroll
  for (int kc = 0; kc < 18; ++kc) {
    int lo = bh + kc * 128;
    float4 flo = *(const float4*)(LDSX + lo);
    float4 fhi = *(const float4*)(LDSX + (lo ^ 16));
    short8 af = mkfrag(flo, fhi);
    if (kc & 1) accB = __builtin_amdgcn_mfma_f32_16x16x32_bf16(af, wf[kc], accB, 0, 0, 0);
    else        accA = __builtin_amdgcn_mfma_f32_16x16x32_bf16(af, wf[kc], accA, 0, 0, 0);
  }
  {   // kc = 18: kgrp 0..2 from hid, kgrp 3 from pos
    int lo = (kgrp == 3 ? bp : bh) + 18 * 128;
    float4 flo = *(const float4*)(LDSX + lo);
    float4 fhi = *(const float4*)(LDSX + (lo ^ 16));
    accA = __builtin_amdgcn_mfma_f32_16x16x32_bf16(mkfrag(flo, fhi), wf[18], accA, 0, 0, 0);
  }
  #pragma unroll
  for (int kc = 19; kc < KCN; ++kc) {
    int lo = bp + kc * 128;
    float4 flo = *(const float4*)(LDSX + lo);
    float4 fhi = *(const float4*)(LDSX + (lo ^ 16));
    short8 af = mkfrag(flo, fhi);
    if (kc & 1) accB = __builtin_amdgcn_mfma_f32_16x16x32_bf16(af, wf[kc], accB, 0, 0, 0);
    else        accA = __builtin_amdgcn_mfma_f32_16x16x32_bf16(af, wf[kc], accA, 0, 0, 0);
  }

  // ---- epilogue: scores = sum_a v[a]*tanh(u1+u2)
  {
    float s0[4];
    #pragma unroll
    for (int r = 0; r < 4; ++r) s0[r] = va * tanhf(accA[r] + accB[r] + u2cur);
    #pragma unroll
    for (int mask = 1; mask < 16; mask <<= 1) {
      #pragma unroll
      for (int r = 0; r < 4; ++r) s0[r] += __shfl_xor(s0[r], mask);
    }
    if (acol == 0) {
      #pragma unroll
      for (int r = 0; r < 4; ++r) scores4[wvix][kgrp * 4 + r] = s0[r];
    }
  }
  __syncthreads();

  // ---- partial softmax over this block's 16 tokens
  if (tid < 64) {
    float s = (tid < MT)
                  ? (scores4[0][tid] + scores4[1][tid] + scores4[2][tid] + scores4[3][tid])
                  : -3.402823466e38f;
    float m = s;
    #pragma unroll
    for (int mask = 1; mask <= 32; mask <<= 1) m = fmaxf(m, __shfl_xor(m, mask));
    float e = (tid < MT) ? expf(s - m) : 0.f;
    float S = e;
    #pragma unroll
    for (int mask = 1; mask <= 32; mask <<= 1) S += __shfl_xor(S, mask);
    if (tid < MT) es_s[tid] = e;
    if (tid == 0) { mS_ws[bq * 2] = m; mS_ws[bq * 2 + 1] = S; }
  }
  __syncthreads();

  // ---- z-partial from fp32 LDS (swizzled read), 150 active lanes
  if (tid < 150) {
    float z0 = 0.f, z1 = 0.f, z2 = 0.f, z3 = 0.f;
    #pragma unroll
    for (int r = 0; r < MT; ++r) {
      int slot = r * RS + ((tid * 16) ^ ((r & 7) << 4));
      float4 x = *(const float4*)(LDSX + slot);
      float e = es_s[r];
      z0 += e * x.x; z1 += e * x.y; z2 += e * x.z; z3 += e * x.w;
    }
    float4 w = {z0, z1, z2, z3};
    *(float4*)(zp_ws + (size_t)bq * 600 + tid * 4) = w;
  }
}

// ---------------- K4: combine 8 partials per b ----------------
__global__ __launch_bounds__(128) void kcomb(const float* __restrict__ zp_ws,
                                             const float* __restrict__ mS_ws,
                                             float* __restrict__ out) {
  int b = blockIdx.x, tid = threadIdx.x;
  float mq[8], Sq[8];
  #pragma unroll
  for (int qq = 0; qq < 8; ++qq) {
    mq[qq] = mS_ws[(b * 8 + qq) * 2];
    Sq[qq] = mS_ws[(b * 8 + qq) * 2 + 1];
  }
  float M = mq[0];
  #pragma unroll
  for (int qq = 1; qq < 8; ++qq) M = fmaxf(M, mq[qq]);
  float c[8], Z = 0.f;
  #pragma unroll
  for (int qq = 0; qq < 8; ++qq) { c[qq] = expf(mq[qq] - M); Z += Sq[qq] * c[qq]; }
  float inv = 1.f / Z;
  for (int d = tid; d < 600; d += 128) {
    float z = 0.f;
    #pragma unroll
    for (int qq = 0; qq < 8; ++qq) z += c[qq] * zp_ws[(size_t)(b * 8 + qq) * 600 + d];
    out[b * 600 + d] = z * inv;
  }
}

extern "C" void kernel_launch(void* const* d_in, const int* in_sizes, int n_in,
                              void* d_out, int out_size, void* d_ws, size_t ws_size,
                              hipStream_t stream) {
  const float* hidden = (const float*)d_in[0];
  const float* pos1   = (const float*)d_in[1];
  const float* pos2   = (const float*)d_in[2];
  const int*   e1     = (const int*)d_in[3];
  const int*   e2     = (const int*)d_in[4];
  const float* Whid   = (const float*)d_in[5];
  const float* Went   = (const float*)d_in[6];
  const float* lt     = (const float*)d_in[7];
  const float* vvec   = (const float*)d_in[8];
  float* out = (float*)d_out;

  char* ws = (char*)d_ws;
  unsigned short* Wt = (unsigned short*)ws;                       //  90,112 B (pad 98,304)
  float* u2ws  = (float*)(ws + 98304);                            // 524,288 B
  float* mS_ws = (float*)(ws + 98304 + 524288);                   // 131,072 B
  float* zp_ws = (float*)(ws + 98304 + 524288 + 131072);          // 39,321,600 B

  hipLaunchKernelGGL(kwprep, dim3(176), dim3(256), 0, stream, Whid, Wt);
  hipLaunchKernelGGL(ku2, dim3(B_ / 2), dim3(256), 0, stream, hidden, e1, e2, Went, lt, u2ws);
  hipLaunchKernelGGL(kmain, dim3(B_ * 8), dim3(256), 0, stream, hidden, pos1, pos2, vvec,
                     Wt, u2ws, zp_ws, mS_ws);
  hipLaunchKernelGGL(kcomb, dim3(B_), dim3(128), 0, stream, zp_ws, mS_ws, out);
}

// Round 11
// 263.852 us; speedup vs baseline: 1.5899x; 1.0060x over previous
//
#include <hip/hip_runtime.h>
#include <hip/hip_bf16.h>
#include <math.h>

// EntityAwareAttention on MI355X.
// K1: W_hid -> bf16, transposed/padded [22 kchunks][64 a][32 k]
// K2: u2[b][a] entity projection (fp32), 2 batches per block
// K3: main fused kernel, 512 threads (8 waves), one block per (b,16-token):
//       split-K: wave w = a-tile (w&3) x K-half (w>>2); wf[11] = 44 VGPR,
//       bf16 Xs staged reg->cvt_pk->LDS (deep load queue, ~14 VALU/thread),
//       K-loop = pure ds_read_b128 + MFMA, partial accs combined via LDS,
//       scores=v.tanh(u1+u2), partial softmax, z-partial from bf16 LDS.
//       __launch_bounds__(512,6) -> 3 blocks/CU = 24 waves/CU (75% occ).
// K4: combine 8 partials per b (log-sum-exp merge), write z.

#define B_    2048
#define L_    128
#define H2_   600
#define P_    50
#define A_    50
#define D700  700
#define KCN   22      // ceil(700/32) -> 704
#define KHALF 11
#define AP    64      // padded attention dim
#define MT    16      // tokens per tile
#define XP    712     // Xs row stride in bf16 elems (704 data + 8 pad)

typedef __attribute__((ext_vector_type(8))) short short8;
typedef __attribute__((ext_vector_type(4))) float f32x4;

__device__ __forceinline__ unsigned short f2bf(float f) {
  unsigned u = __float_as_uint(f);
  u += 0x7fffu + ((u >> 16) & 1u);   // round-to-nearest-even
  return (unsigned short)(u >> 16);
}
__device__ __forceinline__ unsigned cvtpk(float a, float b) {
  unsigned r;
  asm("v_cvt_pk_bf16_f32 %0, %1, %2" : "=v"(r) : "v"(a), "v"(b));
  return r;
}
__device__ __forceinline__ float bf2f(unsigned short s) {
  return __uint_as_float(((unsigned)s) << 16);
}

// ---------------- K1: prep W_hid -> bf16 chunked [kc][a][k] ----------------
__global__ __launch_bounds__(256) void kwprep(const float* __restrict__ Wh,
                                              unsigned short* __restrict__ Wt) {
  int idx = blockIdx.x * 256 + threadIdx.x;
  if (idx >= KCN * 2048) return;
  int kc = idx >> 11, r = idx & 2047, a = r >> 5, kk = r & 31;
  int d = kc * 32 + kk;
  float v = (a < A_ && d < D700) ? Wh[a * D700 + d] : 0.f;
  Wt[idx] = f2bf(v);
}

// ---------------- K2: u2[b][0..63] (fp32), 2 b's per block ----------------
__global__ __launch_bounds__(256) void ku2(const float* __restrict__ hidden,
                                           const int* __restrict__ e1,
                                           const int* __restrict__ e2,
                                           const float* __restrict__ Went,
                                           const float* __restrict__ lt,
                                           float* __restrict__ u2ws) {
  __shared__ __align__(16) float E[2][2400];
  __shared__ float dots[2][2][3];
  __shared__ float aw[2][2][3];
  int tid = threadIdx.x;
  int b0 = blockIdx.x * 2;

  for (int idx = tid; idx < 2 * 2 * 150; idx += 256) {
    int i = idx / 300, r = idx - i * 300, e = r / 150, g = r - e * 150;
    int bb = b0 + i;
    int l = e ? e2[bb] : e1[bb];
    float4 f = *(const float4*)(hidden + ((size_t)bb * L_ + l) * H2_ + g * 4);
    *(float4*)(&E[i][e * 1200 + g * 4]) = f;
  }
  __syncthreads();

  int w = tid >> 6, lane = tid & 63;
  for (int task = w * 3; task < w * 3 + 3; ++task) {
    int i = task / 6, e = (task / 3) & 1, t = task % 3;
    float p = 0.f;
    for (int d = lane; d < 600; d += 64) p += E[i][e * 1200 + d] * lt[t * 600 + d];
    #pragma unroll
    for (int mask = 1; mask <= 32; mask <<= 1) p += __shfl_xor(p, mask);
    if (lane == 0) dots[i][e][t] = p;
  }
  __syncthreads();
  if (tid < 12) {
    int t = tid % 3, e = (tid / 3) & 1, i = tid / 6;
    float d0 = dots[i][e][0], d1 = dots[i][e][1], d2 = dots[i][e][2];
    float m = fmaxf(d0, fmaxf(d1, d2));
    float x0 = expf(d0 - m), x1 = expf(d1 - m), x2 = expf(d2 - m);
    float Z = x0 + x1 + x2;
    aw[i][e][t] = ((t == 0) ? x0 : (t == 1) ? x1 : x2) / Z;
  }
  __syncthreads();
  for (int idx = tid; idx < 2 * 2 * 600; idx += 256) {
    int i = idx / 1200, r = idx - i * 1200, e = r / 600, d = r - e * 600;
    float v = aw[i][e][0] * lt[d] + aw[i][e][1] * lt[600 + d] + aw[i][e][2] * lt[1200 + d];
    E[i][e * 1200 + 600 + d] = v;
  }
  __syncthreads();
  for (int a = w; a < A_; a += 4) {
    float acc[2] = {0.f, 0.f};
    for (int d0 = lane * 4; d0 < 2400; d0 += 256) {
      float4 wv = *(const float4*)(Went + a * 2400 + d0);
      #pragma unroll
      for (int i = 0; i < 2; ++i) {
        float4 ev = *(const float4*)(&E[i][d0]);
        acc[i] += ev.x * wv.x + ev.y * wv.y + ev.z * wv.z + ev.w * wv.w;
      }
    }
    #pragma unroll
    for (int i = 0; i < 2; ++i) {
      float p = acc[i];
      #pragma unroll
      for (int mask = 1; mask <= 32; mask <<= 1) p += __shfl_xor(p, mask);
      if (lane == 0) u2ws[(b0 + i) * AP + a] = p;
    }
  }
  for (int idx = tid; idx < 2 * (AP - A_); idx += 256) {
    u2ws[(b0 + idx / (AP - A_)) * AP + A_ + idx % (AP - A_)] = 0.f;
  }
}

// ---------------- K3: main fused kernel (512 thr, split-K 8 waves) --------
__global__ __launch_bounds__(512, 6) void kmain(
    const float* __restrict__ hidden, const float* __restrict__ pos1,
    const float* __restrict__ pos2, const float* __restrict__ vvec,
    const unsigned short* __restrict__ Wt, const float* __restrict__ u2ws,
    float* __restrict__ zp_ws, float* __restrict__ mS_ws) {
  __shared__ __align__(16) unsigned short Xs[MT * XP];   // 22,784 B
  __shared__ __align__(16) float pacc[4][64][4];         //  4,096 B
  __shared__ float scores4[4][MT];
  __shared__ float es_s[MT];
  __shared__ float u2s[AP];
  __shared__ float vs[AP];

  int tid = threadIdx.x;
  int bq = blockIdx.x;
  int b = bq >> 3, tok0 = (bq & 7) * MT;
  int w = tid >> 6, lane = tid & 63;
  int acol = lane & 15, kgrp = lane >> 4;

  // ======== PHASE 1: issue ALL global loads (deep VMEM queue) ========
  int t = tid >> 5, c0 = tid & 31;          // hidden row t, float4 col c0+32j
  const float* rowp = hidden + ((size_t)(b * L_ + tok0) + t) * H2_;
  float4 f[4];
  #pragma unroll
  for (int j = 0; j < 4; ++j) f[j] = *(const float4*)(rowp + (c0 + 32 * j) * 4);
  bool h5 = (c0 < 22);
  float4 f4;
  if (h5) f4 = *(const float4*)(rowp + (c0 + 128) * 4);

  const float* p1 = pos1 + (size_t)(b * L_ + tok0) * P_;
  const float* p2 = pos2 + (size_t)(b * L_ + tok0) * P_;
  bool hp = (tid < 400);
  float2 q1, q2;
  if (hp) {
    q1 = *(const float2*)(p1 + tid * 2);
    q2 = *(const float2*)(p2 + tid * 2);
  }
  float u2v = 0.f, vvv = 0.f;
  if (tid < AP) {
    u2v = u2ws[b * AP + tid];
    vvv = (tid < A_) ? vvec[tid] : 0.f;
  }

  // ======== PHASE 2: convert (cvt_pk) + LDS writes ========
  #pragma unroll
  for (int j = 0; j < 4; ++j) {
    uint2 wv2; wv2.x = cvtpk(f[j].x, f[j].y); wv2.y = cvtpk(f[j].z, f[j].w);
    *(uint2*)(&Xs[t * XP + (c0 + 32 * j) * 4]) = wv2;
  }
  if (h5) {
    uint2 wv2; wv2.x = cvtpk(f4.x, f4.y); wv2.y = cvtpk(f4.z, f4.w);
    *(uint2*)(&Xs[t * XP + (c0 + 128) * 4]) = wv2;
  }
  if (hp) {
    int t1 = tid / 25, g = tid - t1 * 25;
    *(unsigned*)(&Xs[t1 * XP + 600 + g * 2]) = cvtpk(q1.x, q1.y);
    *(unsigned*)(&Xs[t1 * XP + 650 + g * 2]) = cvtpk(q2.x, q2.y);
  }
  if (tid < MT) {           // zero pad cols 700..703 (8 B per row)
    uint2 zz; zz.x = 0u; zz.y = 0u;
    *(uint2*)(&Xs[tid * XP + 700]) = zz;
  }
  if (tid < AP) { u2s[tid] = u2v; vs[tid] = vvv; }
  __syncthreads();

  // ======== PHASE 3: W half -> regs (44 VGPR), 11-MFMA K-loop ========
  int at = w & 3;                 // a-tile
  int kc0 = (w >> 2) * KHALF;     // K-half start
  const unsigned short* wbase = Wt + (at * 16 + acol) * 32 + kgrp * 8;
  short8 wf[KHALF];
  #pragma unroll
  for (int kc = 0; kc < KHALF; ++kc)
    wf[kc] = *(const short8*)(wbase + (kc0 + kc) * 2048);

  f32x4 acc = {0.f, 0.f, 0.f, 0.f};
  #pragma unroll
  for (int kc = 0; kc < KHALF; ++kc) {
    short8 a0 = *(const short8*)(&Xs[acol * XP + (kc0 + kc) * 32 + kgrp * 8]);
    acc = __builtin_amdgcn_mfma_f32_16x16x32_bf16(a0, wf[kc], acc, 0, 0, 0);
  }

  // ======== PHASE 4: combine K-halves, scores = sum_a v[a]*tanh(u1+u2) ====
  if (w >= 4) {
    float4 pv = {acc[0], acc[1], acc[2], acc[3]};
    *(float4*)(&pacc[w - 4][lane][0]) = pv;
  }
  __syncthreads();
  if (w < 4) {
    float va = vs[w * 16 + acol];
    float u2a = u2s[w * 16 + acol];
    float4 pv = *(const float4*)(&pacc[w][lane][0]);
    float s0[4];
    s0[0] = va * tanhf(acc[0] + pv.x + u2a);
    s0[1] = va * tanhf(acc[1] + pv.y + u2a);
    s0[2] = va * tanhf(acc[2] + pv.z + u2a);
    s0[3] = va * tanhf(acc[3] + pv.w + u2a);
    #pragma unroll
    for (int mask = 1; mask < 16; mask <<= 1) {
      #pragma unroll
      for (int r = 0; r < 4; ++r) s0[r] += __shfl_xor(s0[r], mask);
    }
    if (acol == 0) {
      #pragma unroll
      for (int r = 0; r < 4; ++r) scores4[w][kgrp * 4 + r] = s0[r];
    }
  }
  __syncthreads();

  // ---- partial softmax over this block's 16 tokens (wave 0)
  if (tid < 64) {
    float s = (tid < MT)
                  ? (scores4[0][tid] + scores4[1][tid] + scores4[2][tid] + scores4[3][tid])
                  : -3.402823466e38f;
    float m = s;
    #pragma unroll
    for (int mask = 1; mask <= 32; mask <<= 1) m = fmaxf(m, __shfl_xor(m, mask));
    float e = (tid < MT) ? expf(s - m) : 0.f;
    float S = e;
    #pragma unroll
    for (int mask = 1; mask <= 32; mask <<= 1) S += __shfl_xor(S, mask);
    if (tid < MT) es_s[tid] = e;
    if (tid == 0) { mS_ws[bq * 2] = m; mS_ws[bq * 2 + 1] = S; }
  }
  __syncthreads();

  // ---- z-partial: zp[d] = sum_l exp(s_l - m) * hidden_bf16[l][d]
  if (tid < 150) {
    float z0 = 0.f, z1 = 0.f, z2 = 0.f, z3 = 0.f;
    #pragma unroll
    for (int r = 0; r < MT; ++r) {
      uint2 xv = *(const uint2*)(&Xs[r * XP + tid * 4]);   // 4 bf16
      float e = es_s[r];
      z0 += e * bf2f((unsigned short)(xv.x & 0xffff));
      z1 += e * bf2f((unsigned short)(xv.x >> 16));
      z2 += e * bf2f((unsigned short)(xv.y & 0xffff));
      z3 += e * bf2f((unsigned short)(xv.y >> 16));
    }
    float4 wv = {z0, z1, z2, z3};
    *(float4*)(zp_ws + (size_t)bq * 600 + tid * 4) = wv;
  }
}

// ---------------- K4: combine 8 partials per b ----------------
__global__ __launch_bounds__(128) void kcomb(const float* __restrict__ zp_ws,
                                             const float* __restrict__ mS_ws,
                                             float* __restrict__ out) {
  int b = blockIdx.x, tid = threadIdx.x;
  float mq[8], Sq[8];
  #pragma unroll
  for (int qq = 0; qq < 8; ++qq) {
    mq[qq] = mS_ws[(b * 8 + qq) * 2];
    Sq[qq] = mS_ws[(b * 8 + qq) * 2 + 1];
  }
  float M = mq[0];
  #pragma unroll
  for (int qq = 1; qq < 8; ++qq) M = fmaxf(M, mq[qq]);
  float c[8], Z = 0.f;
  #pragma unroll
  for (int qq = 0; qq < 8; ++qq) { c[qq] = expf(mq[qq] - M); Z += Sq[qq] * c[qq]; }
  float inv = 1.f / Z;
  for (int d = tid; d < 600; d += 128) {
    float z = 0.f;
    #pragma unroll
    for (int qq = 0; qq < 8; ++qq) z += c[qq] * zp_ws[(size_t)(b * 8 + qq) * 600 + d];
    out[b * 600 + d] = z * inv;
  }
}

extern "C" void kernel_launch(void* const* d_in, const int* in_sizes, int n_in,
                              void* d_out, int out_size, void* d_ws, size_t ws_size,
                              hipStream_t stream) {
  const float* hidden = (const float*)d_in[0];
  const float* pos1   = (const float*)d_in[1];
  const float* pos2   = (const float*)d_in[2];
  const int*   e1     = (const int*)d_in[3];
  const int*   e2     = (const int*)d_in[4];
  const float* Whid   = (const float*)d_in[5];
  const float* Went   = (const float*)d_in[6];
  const float* lt     = (const float*)d_in[7];
  const float* vvec   = (const float*)d_in[8];
  float* out = (float*)d_out;

  char* ws = (char*)d_ws;
  unsigned short* Wt = (unsigned short*)ws;                       //  90,112 B (pad 98,304)
  float* u2ws  = (float*)(ws + 98304);                            // 524,288 B
  float* mS_ws = (float*)(ws + 98304 + 524288);                   // 131,072 B
  float* zp_ws = (float*)(ws + 98304 + 524288 + 131072);          // 39,321,600 B

  hipLaunchKernelGGL(kwprep, dim3(176), dim3(256), 0, stream, Whid, Wt);
  hipLaunchKernelGGL(ku2, dim3(B_ / 2), dim3(256), 0, stream, hidden, e1, e2, Went, lt, u2ws);
  hipLaunchKernelGGL(kmain, dim3(B_ * 8), dim3(512), 0, stream, hidden, pos1, pos2, vvec,
                     Wt, u2ws, zp_ws, mS_ws);
  hipLaunchKernelGGL(kcomb, dim3(B_), dim3(128), 0, stream, zp_ws, mS_ws, out);
}

// Round 12
// 256.239 us; speedup vs baseline: 1.6372x; 1.0297x over previous
//
#include <hip/hip_runtime.h>
#include <hip/hip_bf16.h>
#include <math.h>

// EntityAwareAttention on MI355X.
// K1: W_hid -> bf16, transposed/padded [22 kchunks][64 a][32 k]
// K2: u2[b][a] entity projection (fp32), 2 batches per block
// K3: main fused kernel, 512 threads (8 waves), TWO tiles per block with
//     in-block pipelining: issue order [tile0 HBM][wf L2] | B0 | [tile1 HBM]
//     -> counted vmcnt keeps tile1 in flight under tile0's K-loop/epilogue/z;
//     split-K waves (wf[11]=44 VGPR), bf16 Xs[2] double buffer,
//     K-loop = pure ds_read_b128 + MFMA, partial accs combined via LDS.
// K4: combine 8 partials per b (log-sum-exp merge), write z.

#define B_    2048
#define L_    128
#define H2_   600
#define P_    50
#define A_    50
#define D700  700
#define KCN   22      // ceil(700/32) -> 704
#define KHALF 11
#define AP    64      // padded attention dim
#define MT    16      // tokens per tile
#define XP    712     // Xs row stride in bf16 elems (704 data + 8 pad)

typedef __attribute__((ext_vector_type(8))) short short8;
typedef __attribute__((ext_vector_type(4))) float f32x4;

__device__ __forceinline__ unsigned short f2bf(float f) {
  unsigned u = __float_as_uint(f);
  u += 0x7fffu + ((u >> 16) & 1u);   // round-to-nearest-even
  return (unsigned short)(u >> 16);
}
__device__ __forceinline__ unsigned cvtpk(float a, float b) {
  unsigned r;
  asm("v_cvt_pk_bf16_f32 %0, %1, %2" : "=v"(r) : "v"(a), "v"(b));
  return r;
}
__device__ __forceinline__ float bf2f(unsigned short s) {
  return __uint_as_float(((unsigned)s) << 16);
}

// ---------------- K1: prep W_hid -> bf16 chunked [kc][a][k] ----------------
__global__ __launch_bounds__(256) void kwprep(const float* __restrict__ Wh,
                                              unsigned short* __restrict__ Wt) {
  int idx = blockIdx.x * 256 + threadIdx.x;
  if (idx >= KCN * 2048) return;
  int kc = idx >> 11, r = idx & 2047, a = r >> 5, kk = r & 31;
  int d = kc * 32 + kk;
  float v = (a < A_ && d < D700) ? Wh[a * D700 + d] : 0.f;
  Wt[idx] = f2bf(v);
}

// ---------------- K2: u2[b][0..63] (fp32), 2 b's per block ----------------
__global__ __launch_bounds__(256) void ku2(const float* __restrict__ hidden,
                                           const int* __restrict__ e1,
                                           const int* __restrict__ e2,
                                           const float* __restrict__ Went,
                                           const float* __restrict__ lt,
                                           float* __restrict__ u2ws) {
  __shared__ __align__(16) float E[2][2400];
  __shared__ float dots[2][2][3];
  __shared__ float aw[2][2][3];
  int tid = threadIdx.x;
  int b0 = blockIdx.x * 2;

  for (int idx = tid; idx < 2 * 2 * 150; idx += 256) {
    int i = idx / 300, r = idx - i * 300, e = r / 150, g = r - e * 150;
    int bb = b0 + i;
    int l = e ? e2[bb] : e1[bb];
    float4 f = *(const float4*)(hidden + ((size_t)bb * L_ + l) * H2_ + g * 4);
    *(float4*)(&E[i][e * 1200 + g * 4]) = f;
  }
  __syncthreads();

  int w = tid >> 6, lane = tid & 63;
  for (int task = w * 3; task < w * 3 + 3; ++task) {
    int i = task / 6, e = (task / 3) & 1, t = task % 3;
    float p = 0.f;
    for (int d = lane; d < 600; d += 64) p += E[i][e * 1200 + d] * lt[t * 600 + d];
    #pragma unroll
    for (int mask = 1; mask <= 32; mask <<= 1) p += __shfl_xor(p, mask);
    if (lane == 0) dots[i][e][t] = p;
  }
  __syncthreads();
  if (tid < 12) {
    int t = tid % 3, e = (tid / 3) & 1, i = tid / 6;
    float d0 = dots[i][e][0], d1 = dots[i][e][1], d2 = dots[i][e][2];
    float m = fmaxf(d0, fmaxf(d1, d2));
    float x0 = expf(d0 - m), x1 = expf(d1 - m), x2 = expf(d2 - m);
    float Z = x0 + x1 + x2;
    aw[i][e][t] = ((t == 0) ? x0 : (t == 1) ? x1 : x2) / Z;
  }
  __syncthreads();
  for (int idx = tid; idx < 2 * 2 * 600; idx += 256) {
    int i = idx / 1200, r = idx - i * 1200, e = r / 600, d = r - e * 600;
    float v = aw[i][e][0] * lt[d] + aw[i][e][1] * lt[600 + d] + aw[i][e][2] * lt[1200 + d];
    E[i][e * 1200 + 600 + d] = v;
  }
  __syncthreads();
  for (int a = w; a < A_; a += 4) {
    float acc[2] = {0.f, 0.f};
    for (int d0 = lane * 4; d0 < 2400; d0 += 256) {
      float4 wv = *(const float4*)(Went + a * 2400 + d0);
      #pragma unroll
      for (int i = 0; i < 2; ++i) {
        float4 ev = *(const float4*)(&E[i][d0]);
        acc[i] += ev.x * wv.x + ev.y * wv.y + ev.z * wv.z + ev.w * wv.w;
      }
    }
    #pragma unroll
    for (int i = 0; i < 2; ++i) {
      float p = acc[i];
      #pragma unroll
      for (int mask = 1; mask <= 32; mask <<= 1) p += __shfl_xor(p, mask);
      if (lane == 0) u2ws[(b0 + i) * AP + a] = p;
    }
  }
  for (int idx = tid; idx < 2 * (AP - A_); idx += 256) {
    u2ws[(b0 + idx / (AP - A_)) * AP + A_ + idx % (AP - A_)] = 0.f;
  }
}

// ------- K3: main fused kernel (512 thr, split-K, 2-tile pipeline) --------
__global__ __launch_bounds__(512, 4) void kmain(
    const float* __restrict__ hidden, const float* __restrict__ pos1,
    const float* __restrict__ pos2, const float* __restrict__ vvec,
    const unsigned short* __restrict__ Wt, const float* __restrict__ u2ws,
    float* __restrict__ zp_ws, float* __restrict__ mS_ws) {
  __shared__ __align__(16) unsigned short Xs[2][MT * XP];   // 45,568 B
  __shared__ __align__(16) float pacc[4][64][4];            //  4,096 B
  __shared__ float scores4[4][MT];
  __shared__ float es_s[MT];
  __shared__ float u2s[2][AP];
  __shared__ float vs[AP];

  int tid = threadIdx.x;
  int T0 = blockIdx.x * 2, T1 = T0 + 1;
  int b0 = T0 >> 3, tok00 = (T0 & 7) * MT;
  int b1 = T1 >> 3, tok01 = (T1 & 7) * MT;
  int w = tid >> 6, lane = tid & 63;
  int acol = lane & 15, kgrp = lane >> 4;

  int t = tid >> 5, c0 = tid & 31;          // hidden row t, float4 col c0+32j
  bool h5 = (c0 < 22);
  bool hp = (tid < 400);

  // ======== PHASE 1: issue tile0 HBM loads, then wf L2 loads ========
  const float* rowp0 = hidden + ((size_t)(b0 * L_ + tok00) + t) * H2_;
  float4 f0[4];
  #pragma unroll
  for (int j = 0; j < 4; ++j) f0[j] = *(const float4*)(rowp0 + (c0 + 32 * j) * 4);
  float4 f04;
  if (h5) f04 = *(const float4*)(rowp0 + (c0 + 128) * 4);
  const float* p10 = pos1 + (size_t)(b0 * L_ + tok00) * P_;
  const float* p20 = pos2 + (size_t)(b0 * L_ + tok00) * P_;
  float2 q10, q20;
  if (hp) {
    q10 = *(const float2*)(p10 + tid * 2);
    q20 = *(const float2*)(p20 + tid * 2);
  }
  float u2v0 = 0.f, u2v1 = 0.f, vvv = 0.f;
  if (tid < AP) {
    u2v0 = u2ws[b0 * AP + tid];
    u2v1 = u2ws[b1 * AP + tid];
    vvv = (tid < A_) ? vvec[tid] : 0.f;
  }
  // W half -> regs (L2-resident; issued after tile0 so tile0 drains first)
  int at = w & 3;                 // a-tile
  int kc0 = (w >> 2) * KHALF;     // K-half start
  const unsigned short* wbase = Wt + (at * 16 + acol) * 32 + kgrp * 8;
  short8 wf[KHALF];
  #pragma unroll
  for (int kc = 0; kc < KHALF; ++kc)
    wf[kc] = *(const short8*)(wbase + (kc0 + kc) * 2048);

  // ======== PHASE 2: cvt+write tile0 (waits tile0 only; wf in flight) =====
  #pragma unroll
  for (int j = 0; j < 4; ++j) {
    uint2 wv2; wv2.x = cvtpk(f0[j].x, f0[j].y); wv2.y = cvtpk(f0[j].z, f0[j].w);
    *(uint2*)(&Xs[0][t * XP + (c0 + 32 * j) * 4]) = wv2;
  }
  if (h5) {
    uint2 wv2; wv2.x = cvtpk(f04.x, f04.y); wv2.y = cvtpk(f04.z, f04.w);
    *(uint2*)(&Xs[0][t * XP + (c0 + 128) * 4]) = wv2;
  }
  if (hp) {
    int t1 = tid / 25, g = tid - t1 * 25;
    *(unsigned*)(&Xs[0][t1 * XP + 600 + g * 2]) = cvtpk(q10.x, q10.y);
    *(unsigned*)(&Xs[0][t1 * XP + 650 + g * 2]) = cvtpk(q20.x, q20.y);
  }
  if (tid < MT * 2) {        // zero pad cols 700..703 in BOTH buffers
    int hh = tid >> 4;
    uint2 zz; zz.x = 0u; zz.y = 0u;
    *(uint2*)(&Xs[hh][(tid & 15) * XP + 700]) = zz;
  }
  if (tid < AP) { u2s[0][tid] = u2v0; u2s[1][tid] = u2v1; vs[tid] = vvv; }
  __syncthreads();   // B0: Xs[0] ready

  // ======== PHASE 3: issue tile1 HBM loads; K-loop tile0 ========
  const float* rowp1 = hidden + ((size_t)(b1 * L_ + tok01) + t) * H2_;
  float4 g1[4];
  #pragma unroll
  for (int j = 0; j < 4; ++j) g1[j] = *(const float4*)(rowp1 + (c0 + 32 * j) * 4);
  float4 g14;
  if (h5) g14 = *(const float4*)(rowp1 + (c0 + 128) * 4);
  const float* p11 = pos1 + (size_t)(b1 * L_ + tok01) * P_;
  const float* p21 = pos2 + (size_t)(b1 * L_ + tok01) * P_;
  float2 q11, q21;
  if (hp) {
    q11 = *(const float2*)(p11 + tid * 2);
    q21 = *(const float2*)(p21 + tid * 2);
  }

  f32x4 acc = {0.f, 0.f, 0.f, 0.f};
  #pragma unroll
  for (int kc = 0; kc < KHALF; ++kc) {    // waits wf (vmcnt keeps tile1 out)
    short8 a0 = *(const short8*)(&Xs[0][acol * XP + (kc0 + kc) * 32 + kgrp * 8]);
    acc = __builtin_amdgcn_mfma_f32_16x16x32_bf16(a0, wf[kc], acc, 0, 0, 0);
  }

  // ======== PHASE 4: combine K-halves + scores, tile0 ========
  if (w >= 4) {
    float4 pv = {acc[0], acc[1], acc[2], acc[3]};
    *(float4*)(&pacc[w - 4][lane][0]) = pv;
  }
  __syncthreads();   // B1
  if (w < 4) {
    float va = vs[w * 16 + acol];
    float u2a = u2s[0][w * 16 + acol];
    float4 pv = *(const float4*)(&pacc[w][lane][0]);
    float s0[4];
    s0[0] = va * tanhf(acc[0] + pv.x + u2a);
    s0[1] = va * tanhf(acc[1] + pv.y + u2a);
    s0[2] = va * tanhf(acc[2] + pv.z + u2a);
    s0[3] = va * tanhf(acc[3] + pv.w + u2a);
    #pragma unroll
    for (int mask = 1; mask < 16; mask <<= 1) {
      #pragma unroll
      for (int r = 0; r < 4; ++r) s0[r] += __shfl_xor(s0[r], mask);
    }
    if (acol == 0) {
      #pragma unroll
      for (int r = 0; r < 4; ++r) scores4[w][kgrp * 4 + r] = s0[r];
    }
  }
  __syncthreads();   // B2
  if (tid < 64) {
    float s = (tid < MT)
                  ? (scores4[0][tid] + scores4[1][tid] + scores4[2][tid] + scores4[3][tid])
                  : -3.402823466e38f;
    float m = s;
    #pragma unroll
    for (int mask = 1; mask <= 32; mask <<= 1) m = fmaxf(m, __shfl_xor(m, mask));
    float e = (tid < MT) ? expf(s - m) : 0.f;
    float S = e;
    #pragma unroll
    for (int mask = 1; mask <= 32; mask <<= 1) S += __shfl_xor(S, mask);
    if (tid < MT) es_s[tid] = e;
    if (tid == 0) { mS_ws[T0 * 2] = m; mS_ws[T0 * 2 + 1] = S; }
  }
  __syncthreads();   // B3

  // ======== PHASE 5: cvt+write tile1 -> Xs[1] (vmcnt(0), long returned);
  //                    then z-partial tile0 from Xs[0] ========
  #pragma unroll
  for (int j = 0; j < 4; ++j) {
    uint2 wv2; wv2.x = cvtpk(g1[j].x, g1[j].y); wv2.y = cvtpk(g1[j].z, g1[j].w);
    *(uint2*)(&Xs[1][t * XP + (c0 + 32 * j) * 4]) = wv2;
  }
  if (h5) {
    uint2 wv2; wv2.x = cvtpk(g14.x, g14.y); wv2.y = cvtpk(g14.z, g14.w);
    *(uint2*)(&Xs[1][t * XP + (c0 + 128) * 4]) = wv2;
  }
  if (hp) {
    int t1 = tid / 25, g = tid - t1 * 25;
    *(unsigned*)(&Xs[1][t1 * XP + 600 + g * 2]) = cvtpk(q11.x, q11.y);
    *(unsigned*)(&Xs[1][t1 * XP + 650 + g * 2]) = cvtpk(q21.x, q21.y);
  }
  if (tid < 150) {
    float z0 = 0.f, z1 = 0.f, z2 = 0.f, z3 = 0.f;
    #pragma unroll
    for (int r = 0; r < MT; ++r) {
      uint2 xv = *(const uint2*)(&Xs[0][r * XP + tid * 4]);
      float e = es_s[r];
      z0 += e * bf2f((unsigned short)(xv.x & 0xffff));
      z1 += e * bf2f((unsigned short)(xv.x >> 16));
      z2 += e * bf2f((unsigned short)(xv.y & 0xffff));
      z3 += e * bf2f((unsigned short)(xv.y >> 16));
    }
    float4 wv = {z0, z1, z2, z3};
    *(float4*)(zp_ws + (size_t)T0 * 600 + tid * 4) = wv;
  }
  __syncthreads();   // B4: Xs[1] ready, pacc free

  // ======== PHASE 6: K-loop + epilogue + softmax + z, tile1 ========
  f32x4 acc1 = {0.f, 0.f, 0.f, 0.f};
  #pragma unroll
  for (int kc = 0; kc < KHALF; ++kc) {
    short8 a0 = *(const short8*)(&Xs[1][acol * XP + (kc0 + kc) * 32 + kgrp * 8]);
    acc1 = __builtin_amdgcn_mfma_f32_16x16x32_bf16(a0, wf[kc], acc1, 0, 0, 0);
  }
  if (w >= 4) {
    float4 pv = {acc1[0], acc1[1], acc1[2], acc1[3]};
    *(float4*)(&pacc[w - 4][lane][0]) = pv;
  }
  __syncthreads();   // B5
  if (w < 4) {
    float va = vs[w * 16 + acol];
    float u2a = u2s[1][w * 16 + acol];
    float4 pv = *(const float4*)(&pacc[w][lane][0]);
    float s0[4];
    s0[0] = va * tanhf(acc1[0] + pv.x + u2a);
    s0[1] = va * tanhf(acc1[1] + pv.y + u2a);
    s0[2] = va * tanhf(acc1[2] + pv.z + u2a);
    s0[3] = va * tanhf(acc1[3] + pv.w + u2a);
    #pragma unroll
    for (int mask = 1; mask < 16; mask <<= 1) {
      #pragma unroll
      for (int r = 0; r < 4; ++r) s0[r] += __shfl_xor(s0[r], mask);
    }
    if (acol == 0) {
      #pragma unroll
      for (int r = 0; r < 4; ++r) scores4[w][kgrp * 4 + r] = s0[r];
    }
  }
  __syncthreads();   // B6
  if (tid < 64) {
    float s = (tid < MT)
                  ? (scores4[0][tid] + scores4[1][tid] + scores4[2][tid] + scores4[3][tid])
                  : -3.402823466e38f;
    float m = s;
    #pragma unroll
    for (int mask = 1; mask <= 32; mask <<= 1) m = fmaxf(m, __shfl_xor(m, mask));
    float e = (tid < MT) ? expf(s - m) : 0.f;
    float S = e;
    #pragma unroll
    for (int mask = 1; mask <= 32; mask <<= 1) S += __shfl_xor(S, mask);
    if (tid < MT) es_s[tid] = e;
    if (tid == 0) { mS_ws[T1 * 2] = m; mS_ws[T1 * 2 + 1] = S; }
  }
  __syncthreads();   // B7
  if (tid < 150) {
    float z0 = 0.f, z1 = 0.f, z2 = 0.f, z3 = 0.f;
    #pragma unroll
    for (int r = 0; r < MT; ++r) {
      uint2 xv = *(const uint2*)(&Xs[1][r * XP + tid * 4]);
      float e = es_s[r];
      z0 += e * bf2f((unsigned short)(xv.x & 0xffff));
      z1 += e * bf2f((unsigned short)(xv.x >> 16));
      z2 += e * bf2f((unsigned short)(xv.y & 0xffff));
      z3 += e * bf2f((unsigned short)(xv.y >> 16));
    }
    float4 wv = {z0, z1, z2, z3};
    *(float4*)(zp_ws + (size_t)T1 * 600 + tid * 4) = wv;
  }
}

// ---------------- K4: combine 8 partials per b ----------------
__global__ __launch_bounds__(128) void kcomb(const float* __restrict__ zp_ws,
                                             const float* __restrict__ mS_ws,
                                             float* __restrict__ out) {
  int b = blockIdx.x, tid = threadIdx.x;
  float mq[8], Sq[8];
  #pragma unroll
  for (int qq = 0; qq < 8; ++qq) {
    mq[qq] = mS_ws[(b * 8 + qq) * 2];
    Sq[qq] = mS_ws[(b * 8 + qq) * 2 + 1];
  }
  float M = mq[0];
  #pragma unroll
  for (int qq = 1; qq < 8; ++qq) M = fmaxf(M, mq[qq]);
  float c[8], Z = 0.f;
  #pragma unroll
  for (int qq = 0; qq < 8; ++qq) { c[qq] = expf(mq[qq] - M); Z += Sq[qq] * c[qq]; }
  float inv = 1.f / Z;
  for (int d = tid; d < 600; d += 128) {
    float z = 0.f;
    #pragma unroll
    for (int qq = 0; qq < 8; ++qq) z += c[qq] * zp_ws[(size_t)(b * 8 + qq) * 600 + d];
    out[b * 600 + d] = z * inv;
  }
}

extern "C" void kernel_launch(void* const* d_in, const int* in_sizes, int n_in,
                              void* d_out, int out_size, void* d_ws, size_t ws_size,
                              hipStream_t stream) {
  const float* hidden = (const float*)d_in[0];
  const float* pos1   = (const float*)d_in[1];
  const float* pos2   = (const float*)d_in[2];
  const int*   e1     = (const int*)d_in[3];
  const int*   e2     = (const int*)d_in[4];
  const float* Whid   = (const float*)d_in[5];
  const float* Went   = (const float*)d_in[6];
  const float* lt     = (const float*)d_in[7];
  const float* vvec   = (const float*)d_in[8];
  float* out = (float*)d_out;

  char* ws = (char*)d_ws;
  unsigned short* Wt = (unsigned short*)ws;                       //  90,112 B (pad 98,304)
  float* u2ws  = (float*)(ws + 98304);                            // 524,288 B
  float* mS_ws = (float*)(ws + 98304 + 524288);                   // 131,072 B
  float* zp_ws = (float*)(ws + 98304 + 524288 + 131072);          // 39,321,600 B

  hipLaunchKernelGGL(kwprep, dim3(176), dim3(256), 0, stream, Whid, Wt);
  hipLaunchKernelGGL(ku2, dim3(B_ / 2), dim3(256), 0, stream, hidden, e1, e2, Went, lt, u2ws);
  hipLaunchKernelGGL(kmain, dim3(B_ * 4), dim3(512), 0, stream, hidden, pos1, pos2, vvec,
                     Wt, u2ws, zp_ws, mS_ws);
  hipLaunchKernelGGL(kcomb, dim3(B_), dim3(128), 0, stream, zp_ws, mS_ws, out);
}

// Round 13
// 243.973 us; speedup vs baseline: 1.7195x; 1.0503x over previous
//
#include <hip/hip_runtime.h>
#include <hip/hip_bf16.h>
#include <math.h>

// EntityAwareAttention on MI355X.
// K1: W_hid -> bf16, transposed/padded [22 kchunks][64 a][32 k]
// K2: u2[b][a] entity projection (fp32), 2 batches per block
// K3: main fused kernel, 512 threads (8 waves), ONE 32-token tile per block:
//       deep-queue staging (10 loads/thread) -> cvt_pk -> bf16 Xs (45.5 KB),
//       split-K waves: w = a-tile (w&3) x K-half (w>>2), wf[11] = 44 VGPR,
//       K-loop = two independent 11-MFMA chains (token halves),
//       per-32-token epilogue/softmax/z amortizes per-tile fixed costs.
// K4: combine 4 partials per b (log-sum-exp merge), write z.

#define B_    2048
#define L_    128
#define H2_   600
#define P_    50
#define A_    50
#define D700  700
#define KCN   22      // ceil(700/32) -> 704
#define KHALF 11
#define AP    64      // padded attention dim
#define MT    32      // tokens per tile
#define XP    712     // Xs row stride in bf16 elems (704 data + 8 pad)

typedef __attribute__((ext_vector_type(8))) short short8;
typedef __attribute__((ext_vector_type(4))) float f32x4;

__device__ __forceinline__ unsigned short f2bf(float f) {
  unsigned u = __float_as_uint(f);
  u += 0x7fffu + ((u >> 16) & 1u);   // round-to-nearest-even
  return (unsigned short)(u >> 16);
}
__device__ __forceinline__ unsigned cvtpk(float a, float b) {
  unsigned r;
  asm("v_cvt_pk_bf16_f32 %0, %1, %2" : "=v"(r) : "v"(a), "v"(b));
  return r;
}
__device__ __forceinline__ float bf2f(unsigned short s) {
  return __uint_as_float(((unsigned)s) << 16);
}

// ---------------- K1: prep W_hid -> bf16 chunked [kc][a][k] ----------------
__global__ __launch_bounds__(256) void kwprep(const float* __restrict__ Wh,
                                              unsigned short* __restrict__ Wt) {
  int idx = blockIdx.x * 256 + threadIdx.x;
  if (idx >= KCN * 2048) return;
  int kc = idx >> 11, r = idx & 2047, a = r >> 5, kk = r & 31;
  int d = kc * 32 + kk;
  float v = (a < A_ && d < D700) ? Wh[a * D700 + d] : 0.f;
  Wt[idx] = f2bf(v);
}

// ---------------- K2: u2[b][0..63] (fp32), 2 b's per block ----------------
__global__ __launch_bounds__(256) void ku2(const float* __restrict__ hidden,
                                           const int* __restrict__ e1,
                                           const int* __restrict__ e2,
                                           const float* __restrict__ Went,
                                           const float* __restrict__ lt,
                                           float* __restrict__ u2ws) {
  __shared__ __align__(16) float E[2][2400];
  __shared__ float dots[2][2][3];
  __shared__ float aw[2][2][3];
  int tid = threadIdx.x;
  int b0 = blockIdx.x * 2;

  for (int idx = tid; idx < 2 * 2 * 150; idx += 256) {
    int i = idx / 300, r = idx - i * 300, e = r / 150, g = r - e * 150;
    int bb = b0 + i;
    int l = e ? e2[bb] : e1[bb];
    float4 f = *(const float4*)(hidden + ((size_t)bb * L_ + l) * H2_ + g * 4);
    *(float4*)(&E[i][e * 1200 + g * 4]) = f;
  }
  __syncthreads();

  int w = tid >> 6, lane = tid & 63;
  for (int task = w * 3; task < w * 3 + 3; ++task) {
    int i = task / 6, e = (task / 3) & 1, t = task % 3;
    float p = 0.f;
    for (int d = lane; d < 600; d += 64) p += E[i][e * 1200 + d] * lt[t * 600 + d];
    #pragma unroll
    for (int mask = 1; mask <= 32; mask <<= 1) p += __shfl_xor(p, mask);
    if (lane == 0) dots[i][e][t] = p;
  }
  __syncthreads();
  if (tid < 12) {
    int t = tid % 3, e = (tid / 3) & 1, i = tid / 6;
    float d0 = dots[i][e][0], d1 = dots[i][e][1], d2 = dots[i][e][2];
    float m = fmaxf(d0, fmaxf(d1, d2));
    float x0 = expf(d0 - m), x1 = expf(d1 - m), x2 = expf(d2 - m);
    float Z = x0 + x1 + x2;
    aw[i][e][t] = ((t == 0) ? x0 : (t == 1) ? x1 : x2) / Z;
  }
  __syncthreads();
  for (int idx = tid; idx < 2 * 2 * 600; idx += 256) {
    int i = idx / 1200, r = idx - i * 1200, e = r / 600, d = r - e * 600;
    float v = aw[i][e][0] * lt[d] + aw[i][e][1] * lt[600 + d] + aw[i][e][2] * lt[1200 + d];
    E[i][e * 1200 + 600 + d] = v;
  }
  __syncthreads();
  for (int a = w; a < A_; a += 4) {
    float acc[2] = {0.f, 0.f};
    for (int d0 = lane * 4; d0 < 2400; d0 += 256) {
      float4 wv = *(const float4*)(Went + a * 2400 + d0);
      #pragma unroll
      for (int i = 0; i < 2; ++i) {
        float4 ev = *(const float4*)(&E[i][d0]);
        acc[i] += ev.x * wv.x + ev.y * wv.y + ev.z * wv.z + ev.w * wv.w;
      }
    }
    #pragma unroll
    for (int i = 0; i < 2; ++i) {
      float p = acc[i];
      #pragma unroll
      for (int mask = 1; mask <= 32; mask <<= 1) p += __shfl_xor(p, mask);
      if (lane == 0) u2ws[(b0 + i) * AP + a] = p;
    }
  }
  for (int idx = tid; idx < 2 * (AP - A_); idx += 256) {
    u2ws[(b0 + idx / (AP - A_)) * AP + A_ + idx % (AP - A_)] = 0.f;
  }
}

// ------ K3: main fused kernel (512 thr, split-K, 32-token tile) -----------
__global__ __launch_bounds__(512, 4) void kmain(
    const float* __restrict__ hidden, const float* __restrict__ pos1,
    const float* __restrict__ pos2, const float* __restrict__ vvec,
    const unsigned short* __restrict__ Wt, const float* __restrict__ u2ws,
    float* __restrict__ zp_ws, float* __restrict__ mS_ws) {
  __shared__ __align__(16) unsigned short Xs[MT * XP];   // 45,568 B
  __shared__ __align__(16) float pacc[4][64][8];         //  8,192 B
  __shared__ float scores4[4][MT];
  __shared__ float es_s[MT];
  __shared__ float u2s[AP];
  __shared__ float vs[AP];

  int tid = threadIdx.x;
  int T = blockIdx.x;
  int b = T >> 2, tok0 = (T & 3) * MT;
  int w = tid >> 6, lane = tid & 63;
  int acol = lane & 15, kgrp = lane >> 4;

  // ======== PHASE 1: issue ALL tile global loads (deep VMEM queue) ========
  int t = tid >> 4, c0 = tid & 15;          // hidden row t (0..31), f4 col c0+16j
  const float* rowp = hidden + ((size_t)(b * L_ + tok0) + t) * H2_;
  float4 f[9];
  #pragma unroll
  for (int j = 0; j < 9; ++j) f[j] = *(const float4*)(rowp + (c0 + 16 * j) * 4);
  bool h10 = (c0 < 6);
  float4 f9;
  if (h10) f9 = *(const float4*)(rowp + (c0 + 144) * 4);

  const float* p1 = pos1 + (size_t)(b * L_ + tok0) * P_;
  const float* p2 = pos2 + (size_t)(b * L_ + tok0) * P_;
  float2 q1a = *(const float2*)(p1 + tid * 2);
  float2 q2a = *(const float2*)(p2 + tid * 2);
  bool hq = (tid < 288);                    // 800 float2 total: tid + (tid+512)
  float2 q1b, q2b;
  if (hq) {
    q1b = *(const float2*)(p1 + (tid + 512) * 2);
    q2b = *(const float2*)(p2 + (tid + 512) * 2);
  }
  float u2v = 0.f, vvv = 0.f;
  if (tid < AP) {
    u2v = u2ws[b * AP + tid];
    vvv = (tid < A_) ? vvec[tid] : 0.f;
  }

  // ======== PHASE 2: convert + LDS writes (waits tile loads only) ========
  #pragma unroll
  for (int j = 0; j < 9; ++j) {
    uint2 wv2; wv2.x = cvtpk(f[j].x, f[j].y); wv2.y = cvtpk(f[j].z, f[j].w);
    *(uint2*)(&Xs[t * XP + (c0 + 16 * j) * 4]) = wv2;
  }
  if (h10) {
    uint2 wv2; wv2.x = cvtpk(f9.x, f9.y); wv2.y = cvtpk(f9.z, f9.w);
    *(uint2*)(&Xs[t * XP + (c0 + 144) * 4]) = wv2;
  }
  {
    int t1 = tid / 25, g = tid - t1 * 25;
    *(unsigned*)(&Xs[t1 * XP + 600 + g * 2]) = cvtpk(q1a.x, q1a.y);
    *(unsigned*)(&Xs[t1 * XP + 650 + g * 2]) = cvtpk(q2a.x, q2a.y);
  }
  if (hq) {
    int idx = tid + 512;
    int t1 = idx / 25, g = idx - t1 * 25;
    *(unsigned*)(&Xs[t1 * XP + 600 + g * 2]) = cvtpk(q1b.x, q1b.y);
    *(unsigned*)(&Xs[t1 * XP + 650 + g * 2]) = cvtpk(q2b.x, q2b.y);
  }
  if (tid < MT) {           // zero pad cols 700..703
    uint2 zz; zz.x = 0u; zz.y = 0u;
    *(uint2*)(&Xs[tid * XP + 700]) = zz;
  }
  if (tid < AP) { u2s[tid] = u2v; vs[tid] = vvv; }

  // W half -> regs (L2-resident), issued after staging to cap reg pressure
  int at = w & 3;                 // a-tile
  int kc0 = (w >> 2) * KHALF;     // K-half start
  const unsigned short* wbase = Wt + (at * 16 + acol) * 32 + kgrp * 8;
  short8 wf[KHALF];
  #pragma unroll
  for (int kc = 0; kc < KHALF; ++kc)
    wf[kc] = *(const short8*)(wbase + (kc0 + kc) * 2048);
  __syncthreads();

  // ======== PHASE 3: two independent 11-MFMA chains (token halves) ========
  f32x4 acc0 = {0.f, 0.f, 0.f, 0.f}, acc1 = {0.f, 0.f, 0.f, 0.f};
  #pragma unroll
  for (int kc = 0; kc < KHALF; ++kc) {
    int ke = (kc0 + kc) * 32 + kgrp * 8;
    short8 a0 = *(const short8*)(&Xs[acol * XP + ke]);
    short8 a1 = *(const short8*)(&Xs[(16 + acol) * XP + ke]);
    acc0 = __builtin_amdgcn_mfma_f32_16x16x32_bf16(a0, wf[kc], acc0, 0, 0, 0);
    acc1 = __builtin_amdgcn_mfma_f32_16x16x32_bf16(a1, wf[kc], acc1, 0, 0, 0);
  }

  // ======== PHASE 4: combine K-halves + scores ========
  if (w >= 4) {
    float4 pv0 = {acc0[0], acc0[1], acc0[2], acc0[3]};
    float4 pv1 = {acc1[0], acc1[1], acc1[2], acc1[3]};
    *(float4*)(&pacc[w - 4][lane][0]) = pv0;
    *(float4*)(&pacc[w - 4][lane][4]) = pv1;
  }
  __syncthreads();
  if (w < 4) {
    float va = vs[w * 16 + acol];
    float u2a = u2s[w * 16 + acol];
    float4 pv0 = *(const float4*)(&pacc[w][lane][0]);
    float4 pv1 = *(const float4*)(&pacc[w][lane][4]);
    float s0[4], s1[4];
    s0[0] = va * tanhf(acc0[0] + pv0.x + u2a);
    s0[1] = va * tanhf(acc0[1] + pv0.y + u2a);
    s0[2] = va * tanhf(acc0[2] + pv0.z + u2a);
    s0[3] = va * tanhf(acc0[3] + pv0.w + u2a);
    s1[0] = va * tanhf(acc1[0] + pv1.x + u2a);
    s1[1] = va * tanhf(acc1[1] + pv1.y + u2a);
    s1[2] = va * tanhf(acc1[2] + pv1.z + u2a);
    s1[3] = va * tanhf(acc1[3] + pv1.w + u2a);
    #pragma unroll
    for (int mask = 1; mask < 16; mask <<= 1) {
      #pragma unroll
      for (int r = 0; r < 4; ++r) {
        s0[r] += __shfl_xor(s0[r], mask);
        s1[r] += __shfl_xor(s1[r], mask);
      }
    }
    if (acol == 0) {
      #pragma unroll
      for (int r = 0; r < 4; ++r) {
        scores4[w][kgrp * 4 + r] = s0[r];
        scores4[w][16 + kgrp * 4 + r] = s1[r];
      }
    }
  }
  __syncthreads();

  // ---- partial softmax over this block's 32 tokens (wave 0)
  if (tid < 64) {
    float s = (tid < MT)
                  ? (scores4[0][tid] + scores4[1][tid] + scores4[2][tid] + scores4[3][tid])
                  : -3.402823466e38f;
    float m = s;
    #pragma unroll
    for (int mask = 1; mask <= 32; mask <<= 1) m = fmaxf(m, __shfl_xor(m, mask));
    float e = (tid < MT) ? expf(s - m) : 0.f;
    float S = e;
    #pragma unroll
    for (int mask = 1; mask <= 32; mask <<= 1) S += __shfl_xor(S, mask);
    if (tid < MT) es_s[tid] = e;
    if (tid == 0) { mS_ws[T * 2] = m; mS_ws[T * 2 + 1] = S; }
  }
  __syncthreads();

  // ---- z-partial: zp[d] = sum_l exp(s_l - m) * hidden_bf16[l][d]
  if (tid < 150) {
    float z0 = 0.f, z1 = 0.f, z2 = 0.f, z3 = 0.f;
    #pragma unroll
    for (int r = 0; r < MT; ++r) {
      uint2 xv = *(const uint2*)(&Xs[r * XP + tid * 4]);   // 4 bf16
      float e = es_s[r];
      z0 += e * bf2f((unsigned short)(xv.x & 0xffff));
      z1 += e * bf2f((unsigned short)(xv.x >> 16));
      z2 += e * bf2f((unsigned short)(xv.y & 0xffff));
      z3 += e * bf2f((unsigned short)(xv.y >> 16));
    }
    float4 wv = {z0, z1, z2, z3};
    *(float4*)(zp_ws + (size_t)T * 600 + tid * 4) = wv;
  }
}

// ---------------- K4: combine 4 partials per b ----------------
__global__ __launch_bounds__(128) void kcomb(const float* __restrict__ zp_ws,
                                             const float* __restrict__ mS_ws,
                                             float* __restrict__ out) {
  int b = blockIdx.x, tid = threadIdx.x;
  float mq[4], Sq[4];
  #pragma unroll
  for (int qq = 0; qq < 4; ++qq) {
    mq[qq] = mS_ws[(b * 4 + qq) * 2];
    Sq[qq] = mS_ws[(b * 4 + qq) * 2 + 1];
  }
  float M = fmaxf(fmaxf(mq[0], mq[1]), fmaxf(mq[2], mq[3]));
  float c[4], Z = 0.f;
  #pragma unroll
  for (int qq = 0; qq < 4; ++qq) { c[qq] = expf(mq[qq] - M); Z += Sq[qq] * c[qq]; }
  float inv = 1.f / Z;
  for (int d = tid; d < 600; d += 128) {
    float z = 0.f;
    #pragma unroll
    for (int qq = 0; qq < 4; ++qq) z += c[qq] * zp_ws[(size_t)(b * 4 + qq) * 600 + d];
    out[b * 600 + d] = z * inv;
  }
}

extern "C" void kernel_launch(void* const* d_in, const int* in_sizes, int n_in,
                              void* d_out, int out_size, void* d_ws, size_t ws_size,
                              hipStream_t stream) {
  const float* hidden = (const float*)d_in[0];
  const float* pos1   = (const float*)d_in[1];
  const float* pos2   = (const float*)d_in[2];
  const int*   e1     = (const int*)d_in[3];
  const int*   e2     = (const int*)d_in[4];
  const float* Whid   = (const float*)d_in[5];
  const float* Went   = (const float*)d_in[6];
  const float* lt     = (const float*)d_in[7];
  const float* vvec   = (const float*)d_in[8];
  float* out = (float*)d_out;

  char* ws = (char*)d_ws;
  unsigned short* Wt = (unsigned short*)ws;                       //  90,112 B (pad 98,304)
  float* u2ws  = (float*)(ws + 98304);                            // 524,288 B
  float* mS_ws = (float*)(ws + 98304 + 524288);                   // 131,072 B
  float* zp_ws = (float*)(ws + 98304 + 524288 + 131072);          // 19,660,800 B

  hipLaunchKernelGGL(kwprep, dim3(176), dim3(256), 0, stream, Whid, Wt);
  hipLaunchKernelGGL(ku2, dim3(B_ / 2), dim3(256), 0, stream, hidden, e1, e2, Went, lt, u2ws);
  hipLaunchKernelGGL(kmain, dim3(B_ * 4), dim3(512), 0, stream, hidden, pos1, pos2, vvec,
                     Wt, u2ws, zp_ws, mS_ws);
  hipLaunchKernelGGL(kcomb, dim3(B_), dim3(128), 0, stream, zp_ws, mS_ws, out);
}

// Round 14
// 224.068 us; speedup vs baseline: 1.8722x; 1.0888x over previous
//
#include <hip/hip_runtime.h>
#include <hip/hip_bf16.h>
#include <math.h>

// EntityAwareAttention on MI355X.
// K2 (ku2): FUSED W_hid prep + u2 entity projection.
//     - kwprep work folded in (45056 elems over grid 256x512)
//     - 8 batches/block (W_ent L2 traffic 491->123 MB), E[8][2400] fp32 LDS
// K3 (kmain): unchanged from R13 best (244 us): 512 thr, split-K 8 waves,
//     one 32-token tile, deep-queue staging -> cvt_pk -> bf16 Xs,
//     two 11-MFMA chains, per-32-token softmax + z-partial.
// K4 (kcomb): combine 4 partials per b (log-sum-exp), write z.

#define B_    2048
#define L_    128
#define H2_   600
#define P_    50
#define A_    50
#define D700  700
#define KCN   22      // ceil(700/32) -> 704
#define KHALF 11
#define AP    64      // padded attention dim
#define MT    32      // tokens per tile
#define XP    712     // Xs row stride in bf16 elems (704 data + 8 pad)
#define NB    8       // batches per ku2 block

typedef __attribute__((ext_vector_type(8))) short short8;
typedef __attribute__((ext_vector_type(4))) float f32x4;

__device__ __forceinline__ unsigned short f2bf(float f) {
  unsigned u = __float_as_uint(f);
  u += 0x7fffu + ((u >> 16) & 1u);   // round-to-nearest-even
  return (unsigned short)(u >> 16);
}
__device__ __forceinline__ unsigned cvtpk(float a, float b) {
  unsigned r;
  asm("v_cvt_pk_bf16_f32 %0, %1, %2" : "=v"(r) : "v"(a), "v"(b));
  return r;
}
__device__ __forceinline__ float bf2f(unsigned short s) {
  return __uint_as_float(((unsigned)s) << 16);
}

// ------- K2: fused W_hid prep + u2[b][0..63], 8 batches per block ---------
__global__ __launch_bounds__(512, 4) void ku2(const float* __restrict__ hidden,
                                              const int* __restrict__ e1,
                                              const int* __restrict__ e2,
                                              const float* __restrict__ Went,
                                              const float* __restrict__ lt,
                                              const float* __restrict__ Wh,
                                              unsigned short* __restrict__ Wt,
                                              float* __restrict__ u2ws) {
  __shared__ __align__(16) float E[NB][2400];   // 76,800 B
  __shared__ float dots[NB][2][3];
  __shared__ float aw[NB][2][3];
  int tid = threadIdx.x;
  int b0 = blockIdx.x * NB;

  // ---- fused kwprep: Wt[kc][a][k] bf16 (45,056 elems over 131,072 threads)
  {
    int gidx = blockIdx.x * 512 + tid;
    if (gidx < KCN * 2048) {
      int kc = gidx >> 11, r = gidx & 2047, a = r >> 5, kk = r & 31;
      int d = kc * 32 + kk;
      float v = (a < A_ && d < D700) ? Wh[a * D700 + d] : 0.f;
      Wt[gidx] = f2bf(v);
    }
  }

  // ---- gather entity rows: NB x 2 x 150 float4
  for (int idx = tid; idx < NB * 2 * 150; idx += 512) {
    int i = idx / 300, r = idx - i * 300, e = r / 150, g = r - e * 150;
    int bb = b0 + i;
    int l = e ? e2[bb] : e1[bb];
    float4 f = *(const float4*)(hidden + ((size_t)bb * L_ + l) * H2_ + g * 4);
    *(float4*)(&E[i][e * 1200 + g * 4]) = f;
  }
  __syncthreads();

  int w = tid >> 6, lane = tid & 63;
  // ---- 48 dot products: wave w -> i=w, 6 tasks (e = j>=3, t = j%3)
  #pragma unroll
  for (int j = 0; j < 6; ++j) {
    int i = w, e = (j >= 3) ? 1 : 0, t = j % 3;
    float p = 0.f;
    for (int d = lane; d < 600; d += 64) p += E[i][e * 1200 + d] * lt[t * 600 + d];
    #pragma unroll
    for (int mask = 1; mask <= 32; mask <<= 1) p += __shfl_xor(p, mask);
    if (lane == 0) dots[i][e][t] = p;
  }
  __syncthreads();
  if (tid < NB * 6) {
    int t = tid % 3, e = (tid / 3) & 1, i = tid / 6;
    float d0 = dots[i][e][0], d1 = dots[i][e][1], d2 = dots[i][e][2];
    float m = fmaxf(d0, fmaxf(d1, d2));
    float x0 = expf(d0 - m), x1 = expf(d1 - m), x2 = expf(d2 - m);
    float Z = x0 + x1 + x2;
    aw[i][e][t] = ((t == 0) ? x0 : (t == 1) ? x1 : x2) / Z;
  }
  __syncthreads();
  // ---- e_type fill
  for (int idx = tid; idx < NB * 2 * 600; idx += 512) {
    int i = idx / 1200, r = idx - i * 1200, e = r / 600, d = r - e * 600;
    float v = aw[i][e][0] * lt[d] + aw[i][e][1] * lt[600 + d] + aw[i][e][2] * lt[1200 + d];
    E[i][e * 1200 + 600 + d] = v;
  }
  __syncthreads();
  // ---- u2: wave w handles a = w, w+8, ... ; acc over 8 batches
  for (int a = w; a < A_; a += 8) {
    float acc[NB] = {0.f, 0.f, 0.f, 0.f, 0.f, 0.f, 0.f, 0.f};
    for (int d0 = lane * 4; d0 < 2400; d0 += 256) {
      float4 wv = *(const float4*)(Went + a * 2400 + d0);
      #pragma unroll
      for (int i = 0; i < NB; ++i) {
        float4 ev = *(const float4*)(&E[i][d0]);
        acc[i] += ev.x * wv.x + ev.y * wv.y + ev.z * wv.z + ev.w * wv.w;
      }
    }
    #pragma unroll
    for (int i = 0; i < NB; ++i) {
      float p = acc[i];
      #pragma unroll
      for (int mask = 1; mask <= 32; mask <<= 1) p += __shfl_xor(p, mask);
      if (lane == 0) u2ws[(b0 + i) * AP + a] = p;
    }
  }
  // ---- zero pad a = 50..63
  for (int idx = tid; idx < NB * (AP - A_); idx += 512) {
    u2ws[(b0 + idx / (AP - A_)) * AP + A_ + idx % (AP - A_)] = 0.f;
  }
}

// ------ K3: main fused kernel (512 thr, split-K, 32-token tile) -----------
__global__ __launch_bounds__(512, 4) void kmain(
    const float* __restrict__ hidden, const float* __restrict__ pos1,
    const float* __restrict__ pos2, const float* __restrict__ vvec,
    const unsigned short* __restrict__ Wt, const float* __restrict__ u2ws,
    float* __restrict__ zp_ws, float* __restrict__ mS_ws) {
  __shared__ __align__(16) unsigned short Xs[MT * XP];   // 45,568 B
  __shared__ __align__(16) float pacc[4][64][8];         //  8,192 B
  __shared__ float scores4[4][MT];
  __shared__ float es_s[MT];
  __shared__ float u2s[AP];
  __shared__ float vs[AP];

  int tid = threadIdx.x;
  int T = blockIdx.x;
  int b = T >> 2, tok0 = (T & 3) * MT;
  int w = tid >> 6, lane = tid & 63;
  int acol = lane & 15, kgrp = lane >> 4;

  // ======== PHASE 1: issue ALL tile global loads (deep VMEM queue) ========
  int t = tid >> 4, c0 = tid & 15;          // hidden row t (0..31), f4 col c0+16j
  const float* rowp = hidden + ((size_t)(b * L_ + tok0) + t) * H2_;
  float4 f[9];
  #pragma unroll
  for (int j = 0; j < 9; ++j) f[j] = *(const float4*)(rowp + (c0 + 16 * j) * 4);
  bool h10 = (c0 < 6);
  float4 f9;
  if (h10) f9 = *(const float4*)(rowp + (c0 + 144) * 4);

  const float* p1 = pos1 + (size_t)(b * L_ + tok0) * P_;
  const float* p2 = pos2 + (size_t)(b * L_ + tok0) * P_;
  float2 q1a = *(const float2*)(p1 + tid * 2);
  float2 q2a = *(const float2*)(p2 + tid * 2);
  bool hq = (tid < 288);                    // 800 float2 total: tid + (tid+512)
  float2 q1b, q2b;
  if (hq) {
    q1b = *(const float2*)(p1 + (tid + 512) * 2);
    q2b = *(const float2*)(p2 + (tid + 512) * 2);
  }
  float u2v = 0.f, vvv = 0.f;
  if (tid < AP) {
    u2v = u2ws[b * AP + tid];
    vvv = (tid < A_) ? vvec[tid] : 0.f;
  }

  // ======== PHASE 2: convert + LDS writes (waits tile loads only) ========
  #pragma unroll
  for (int j = 0; j < 9; ++j) {
    uint2 wv2; wv2.x = cvtpk(f[j].x, f[j].y); wv2.y = cvtpk(f[j].z, f[j].w);
    *(uint2*)(&Xs[t * XP + (c0 + 16 * j) * 4]) = wv2;
  }
  if (h10) {
    uint2 wv2; wv2.x = cvtpk(f9.x, f9.y); wv2.y = cvtpk(f9.z, f9.w);
    *(uint2*)(&Xs[t * XP + (c0 + 144) * 4]) = wv2;
  }
  {
    int t1 = tid / 25, g = tid - t1 * 25;
    *(unsigned*)(&Xs[t1 * XP + 600 + g * 2]) = cvtpk(q1a.x, q1a.y);
    *(unsigned*)(&Xs[t1 * XP + 650 + g * 2]) = cvtpk(q2a.x, q2a.y);
  }
  if (hq) {
    int idx = tid + 512;
    int t1 = idx / 25, g = idx - t1 * 25;
    *(unsigned*)(&Xs[t1 * XP + 600 + g * 2]) = cvtpk(q1b.x, q1b.y);
    *(unsigned*)(&Xs[t1 * XP + 650 + g * 2]) = cvtpk(q2b.x, q2b.y);
  }
  if (tid < MT) {           // zero pad cols 700..703
    uint2 zz; zz.x = 0u; zz.y = 0u;
    *(uint2*)(&Xs[tid * XP + 700]) = zz;
  }
  if (tid < AP) { u2s[tid] = u2v; vs[tid] = vvv; }

  // W half -> regs (L2-resident), issued after staging to cap reg pressure
  int at = w & 3;                 // a-tile
  int kc0 = (w >> 2) * KHALF;     // K-half start
  const unsigned short* wbase = Wt + (at * 16 + acol) * 32 + kgrp * 8;
  short8 wf[KHALF];
  #pragma unroll
  for (int kc = 0; kc < KHALF; ++kc)
    wf[kc] = *(const short8*)(wbase + (kc0 + kc) * 2048);
  __syncthreads();

  // ======== PHASE 3: two independent 11-MFMA chains (token halves) ========
  f32x4 acc0 = {0.f, 0.f, 0.f, 0.f}, acc1 = {0.f, 0.f, 0.f, 0.f};
  #pragma unroll
  for (int kc = 0; kc < KHALF; ++kc) {
    int ke = (kc0 + kc) * 32 + kgrp * 8;
    short8 a0 = *(const short8*)(&Xs[acol * XP + ke]);
    short8 a1 = *(const short8*)(&Xs[(16 + acol) * XP + ke]);
    acc0 = __builtin_amdgcn_mfma_f32_16x16x32_bf16(a0, wf[kc], acc0, 0, 0, 0);
    acc1 = __builtin_amdgcn_mfma_f32_16x16x32_bf16(a1, wf[kc], acc1, 0, 0, 0);
  }

  // ======== PHASE 4: combine K-halves + scores ========
  if (w >= 4) {
    float4 pv0 = {acc0[0], acc0[1], acc0[2], acc0[3]};
    float4 pv1 = {acc1[0], acc1[1], acc1[2], acc1[3]};
    *(float4*)(&pacc[w - 4][lane][0]) = pv0;
    *(float4*)(&pacc[w - 4][lane][4]) = pv1;
  }
  __syncthreads();
  if (w < 4) {
    float va = vs[w * 16 + acol];
    float u2a = u2s[w * 16 + acol];
    float4 pv0 = *(const float4*)(&pacc[w][lane][0]);
    float4 pv1 = *(const float4*)(&pacc[w][lane][4]);
    float s0[4], s1[4];
    s0[0] = va * tanhf(acc0[0] + pv0.x + u2a);
    s0[1] = va * tanhf(acc0[1] + pv0.y + u2a);
    s0[2] = va * tanhf(acc0[2] + pv0.z + u2a);
    s0[3] = va * tanhf(acc0[3] + pv0.w + u2a);
    s1[0] = va * tanhf(acc1[0] + pv1.x + u2a);
    s1[1] = va * tanhf(acc1[1] + pv1.y + u2a);
    s1[2] = va * tanhf(acc1[2] + pv1.z + u2a);
    s1[3] = va * tanhf(acc1[3] + pv1.w + u2a);
    #pragma unroll
    for (int mask = 1; mask < 16; mask <<= 1) {
      #pragma unroll
      for (int r = 0; r < 4; ++r) {
        s0[r] += __shfl_xor(s0[r], mask);
        s1[r] += __shfl_xor(s1[r], mask);
      }
    }
    if (acol == 0) {
      #pragma unroll
      for (int r = 0; r < 4; ++r) {
        scores4[w][kgrp * 4 + r] = s0[r];
        scores4[w][16 + kgrp * 4 + r] = s1[r];
      }
    }
  }
  __syncthreads();

  // ---- partial softmax over this block's 32 tokens (wave 0)
  if (tid < 64) {
    float s = (tid < MT)
                  ? (scores4[0][tid] + scores4[1][tid] + scores4[2][tid] + scores4[3][tid])
                  : -3.402823466e38f;
    float m = s;
    #pragma unroll
    for (int mask = 1; mask <= 32; mask <<= 1) m = fmaxf(m, __shfl_xor(m, mask));
    float e = (tid < MT) ? expf(s - m) : 0.f;
    float S = e;
    #pragma unroll
    for (int mask = 1; mask <= 32; mask <<= 1) S += __shfl_xor(S, mask);
    if (tid < MT) es_s[tid] = e;
    if (tid == 0) { mS_ws[T * 2] = m; mS_ws[T * 2 + 1] = S; }
  }
  __syncthreads();

  // ---- z-partial: zp[d] = sum_l exp(s_l - m) * hidden_bf16[l][d]
  if (tid < 150) {
    float z0 = 0.f, z1 = 0.f, z2 = 0.f, z3 = 0.f;
    #pragma unroll
    for (int r = 0; r < MT; ++r) {
      uint2 xv = *(const uint2*)(&Xs[r * XP + tid * 4]);   // 4 bf16
      float e = es_s[r];
      z0 += e * bf2f((unsigned short)(xv.x & 0xffff));
      z1 += e * bf2f((unsigned short)(xv.x >> 16));
      z2 += e * bf2f((unsigned short)(xv.y & 0xffff));
      z3 += e * bf2f((unsigned short)(xv.y >> 16));
    }
    float4 wv = {z0, z1, z2, z3};
    *(float4*)(zp_ws + (size_t)T * 600 + tid * 4) = wv;
  }
}

// ---------------- K4: combine 4 partials per b ----------------
__global__ __launch_bounds__(128) void kcomb(const float* __restrict__ zp_ws,
                                             const float* __restrict__ mS_ws,
                                             float* __restrict__ out) {
  int b = blockIdx.x, tid = threadIdx.x;
  float mq[4], Sq[4];
  #pragma unroll
  for (int qq = 0; qq < 4; ++qq) {
    mq[qq] = mS_ws[(b * 4 + qq) * 2];
    Sq[qq] = mS_ws[(b * 4 + qq) * 2 + 1];
  }
  float M = fmaxf(fmaxf(mq[0], mq[1]), fmaxf(mq[2], mq[3]));
  float c[4], Z = 0.f;
  #pragma unroll
  for (int qq = 0; qq < 4; ++qq) { c[qq] = expf(mq[qq] - M); Z += Sq[qq] * c[qq]; }
  float inv = 1.f / Z;
  for (int d = tid; d < 600; d += 128) {
    float z = 0.f;
    #pragma unroll
    for (int qq = 0; qq < 4; ++qq) z += c[qq] * zp_ws[(size_t)(b * 4 + qq) * 600 + d];
    out[b * 600 + d] = z * inv;
  }
}

extern "C" void kernel_launch(void* const* d_in, const int* in_sizes, int n_in,
                              void* d_out, int out_size, void* d_ws, size_t ws_size,
                              hipStream_t stream) {
  const float* hidden = (const float*)d_in[0];
  const float* pos1   = (const float*)d_in[1];
  const float* pos2   = (const float*)d_in[2];
  const int*   e1     = (const int*)d_in[3];
  const int*   e2     = (const int*)d_in[4];
  const float* Whid   = (const float*)d_in[5];
  const float* Went   = (const float*)d_in[6];
  const float* lt     = (const float*)d_in[7];
  const float* vvec   = (const float*)d_in[8];
  float* out = (float*)d_out;

  char* ws = (char*)d_ws;
  unsigned short* Wt = (unsigned short*)ws;                       //  90,112 B (pad 98,304)
  float* u2ws  = (float*)(ws + 98304);                            // 524,288 B
  float* mS_ws = (float*)(ws + 98304 + 524288);                   // 131,072 B
  float* zp_ws = (float*)(ws + 98304 + 524288 + 131072);          // 19,660,800 B

  hipLaunchKernelGGL(ku2, dim3(B_ / NB), dim3(512), 0, stream, hidden, e1, e2, Went, lt,
                     Whid, Wt, u2ws);
  hipLaunchKernelGGL(kmain, dim3(B_ * 4), dim3(512), 0, stream, hidden, pos1, pos2, vvec,
                     Wt, u2ws, zp_ws, mS_ws);
  hipLaunchKernelGGL(kcomb, dim3(B_), dim3(128), 0, stream, zp_ws, mS_ws, out);
}